// Round 2
// baseline (470.641 us; speedup 1.0000x reference)
//
#include <hip/hip_runtime.h>
#include <cstdint>
#include <cstddef>

// Poincare-ball (hyperbolic) attention block, fp32 baseline.
// B=2, S=2048, D=256, H=8, dh=32, c=1.
//
// Pipeline:
//   1) gemm_nt<1> x3 : Q/K/V = x @ W^T + b, written head-major [bh][s][32]
//   2) expmap_qk     : expmap0 on Q,K rows (dh=32 vectors) + qq/kk precompute
//   3) attn_part     : per (s-tile, t-chunk, bh): accumulate num[32]/den partials
//                      scores = -dist/sqrt(dh); dist via closed-form Mobius norm;
//                      NOTE scores in [-2.16, 0] so no online max needed.
//   4) combine       : sum 4 t-chunk partials, divide, write [B,S,D]
//   5) gemm_nt<0> x2 : @ Wo^T + bo, then @ Wfc^T + bfc -> d_out

#define INV_SQRT_DH 0.17677669529663687f  // 1/sqrt(32)
#define CLIP_HI 0.99999f                  // 1 - 1e-5

__device__ __forceinline__ float fast_log2(float x) { return __builtin_amdgcn_logf(x); }
__device__ __forceinline__ float fast_exp2(float x) { return __builtin_amdgcn_exp2f(x); }

// ---------------------------------------------------------------------------
// fp32 GEMM: C[M=4096, N=256] = A[4096,256] @ W[256,256]^T + bias
// 64x64 tile, BK=32, 256 threads, 4x4 micro-tile.
// OUTMODE 0: row-major C[m*256+n].  OUTMODE 1: head-major Q[bh][s][dh].
template<int OUTMODE>
__global__ __launch_bounds__(256)
void gemm_nt(const float* __restrict__ A, const float* __restrict__ W,
             const float* __restrict__ bias, float* __restrict__ C) {
  __shared__ float As[64][36];  // pad 36: keeps 16B alignment, 2-way bank alias (free)
  __shared__ float Ws[64][36];
  const int tid = threadIdx.x;
  const int m0 = blockIdx.x * 64;
  const int n0 = blockIdx.y * 64;
  const int ty = tid >> 4, tx = tid & 15;
  float acc[4][4] = {};
  for (int k0 = 0; k0 < 256; k0 += 32) {
#pragma unroll
    for (int jj = 0; jj < 2; ++jj) {
      int j = tid * 2 + jj;          // 512 float4 per tile
      int r = j >> 3, c4 = (j & 7) << 2;
      *(float4*)&As[r][c4] = *(const float4*)&A[(size_t)(m0 + r) * 256 + k0 + c4];
      *(float4*)&Ws[r][c4] = *(const float4*)&W[(size_t)(n0 + r) * 256 + k0 + c4];
    }
    __syncthreads();
#pragma unroll
    for (int kk = 0; kk < 32; ++kk) {
      float a[4], b[4];
#pragma unroll
      for (int i = 0; i < 4; ++i) a[i] = As[ty * 4 + i][kk];
#pragma unroll
      for (int j = 0; j < 4; ++j) b[j] = Ws[tx * 4 + j][kk];
#pragma unroll
      for (int i = 0; i < 4; ++i)
#pragma unroll
        for (int j = 0; j < 4; ++j)
          acc[i][j] = fmaf(a[i], b[j], acc[i][j]);
    }
    __syncthreads();
  }
#pragma unroll
  for (int i = 0; i < 4; ++i) {
    int m = m0 + ty * 4 + i;
    float4 o;
    o.x = acc[i][0] + bias[n0 + tx * 4 + 0];
    o.y = acc[i][1] + bias[n0 + tx * 4 + 1];
    o.z = acc[i][2] + bias[n0 + tx * 4 + 2];
    o.w = acc[i][3] + bias[n0 + tx * 4 + 3];
    if (OUTMODE == 0) {
      *(float4*)&C[(size_t)m * 256 + n0 + tx * 4] = o;
    } else {
      int n = n0 + tx * 4;          // 4 cols stay within one head (n%32 in {0..28})
      int h = n >> 5, d = n & 31;
      int b = m >> 11, s = m & 2047;
      *(float4*)&C[((size_t)((b << 3) + h) << 16) + (size_t)s * 32 + d] = o;
    }
  }
}

// ---------------------------------------------------------------------------
// expmap0 at origin on each dh=32 vector of Q and K (in place) + store |.|^2.
// idx < 32768 -> Q row, else K row. qq = tanh(norm)^2 (== |mapped|^2, c=1).
__global__ __launch_bounds__(256)
void expmap_qk(float* __restrict__ Q, float* __restrict__ K,
               float* __restrict__ QQ, float* __restrict__ KK) {
  int idx = blockIdx.x * 256 + threadIdx.x;   // 0..65535
  float* base;
  float* qqout;
  if (idx < 32768) { base = Q + (size_t)idx * 32; qqout = QQ + idx; }
  else             { int i2 = idx - 32768; base = K + (size_t)i2 * 32; qqout = KK + i2; }
  float4 v[8];
  float ss = 0.0f;
#pragma unroll
  for (int i = 0; i < 8; ++i) {
    v[i] = *(const float4*)&base[i * 4];
    ss = fmaf(v[i].x, v[i].x, ss);
    ss = fmaf(v[i].y, v[i].y, ss);
    ss = fmaf(v[i].z, v[i].z, ss);
    ss = fmaf(v[i].w, v[i].w, ss);
  }
  ss = fmaxf(ss, 1e-12f);
  float norm = sqrtf(ss);
  float t = tanhf(norm);
  float sc = t / norm;
#pragma unroll
  for (int i = 0; i < 8; ++i) {
    v[i].x *= sc; v[i].y *= sc; v[i].z *= sc; v[i].w *= sc;
    *(float4*)&base[i * 4] = v[i];
  }
  *qqout = t * t;
}

// ---------------------------------------------------------------------------
// Attention partial: each thread owns one q row; block covers 256 rows of one
// (bh) and one quarter of the t range (512 t values, staged in 128-row tiles).
__global__ __launch_bounds__(256)
void attn_part(const float* __restrict__ Q, const float* __restrict__ Kb,
               const float* __restrict__ Vb, const float* __restrict__ QQ,
               const float* __restrict__ KKa,
               float* __restrict__ PN, float* __restrict__ PD) {
  __shared__ float Ks[128 * 32];
  __shared__ float Vs[128 * 32];
  __shared__ float kks[128];
  const int tid = threadIdx.x;
  const int bh = blockIdx.z;                   // 0..15
  const int s  = blockIdx.x * 256 + tid;       // q row in [0,2048)
  const int tc = blockIdx.y;                   // t-chunk 0..3

  const float* qrow = Q + ((size_t)bh << 16) + (size_t)s * 32;
  float q[32];
#pragma unroll
  for (int i = 0; i < 8; ++i) {
    float4 v4 = *(const float4*)&qrow[i * 4];
    q[i * 4 + 0] = v4.x; q[i * 4 + 1] = v4.y;
    q[i * 4 + 2] = v4.z; q[i * 4 + 3] = v4.w;
  }
  const float qq = QQ[bh * 2048 + s];
  const float Bq = 1.0f - qq;
  float acc[32] = {};
  float den = 0.0f;
  const float* Kp = Kb + ((size_t)bh << 16);
  const float* Vp = Vb + ((size_t)bh << 16);
  const float* kkp = KKa + bh * 2048;
  const int t0c = tc * 512;

  for (int t0 = t0c; t0 < t0c + 512; t0 += 128) {
    __syncthreads();
#pragma unroll
    for (int u = 0; u < 4; ++u) {
      int j = u * 256 + tid;                   // float4 index 0..1023
      *(float4*)&Ks[j * 4] = *(const float4*)&Kp[(size_t)t0 * 32 + j * 4];
      *(float4*)&Vs[j * 4] = *(const float4*)&Vp[(size_t)t0 * 32 + j * 4];
    }
    if (tid < 128) kks[tid] = kkp[t0 + tid];
    __syncthreads();

    for (int tt = 0; tt < 128; ++tt) {
      const float* kr = &Ks[tt * 32];
      float qk = 0.0f;
#pragma unroll
      for (int i = 0; i < 8; ++i) {
        float4 kv = *(const float4*)&kr[i * 4];
        qk = fmaf(q[i * 4 + 0], kv.x, qk);
        qk = fmaf(q[i * 4 + 1], kv.y, qk);
        qk = fmaf(q[i * 4 + 2], kv.z, qk);
        qk = fmaf(q[i * 4 + 3], kv.w, qk);
      }
      float kkt = kks[tt];
      // c = 1 closed-form Mobius-add norm
      float Af   = 1.0f - 2.0f * qk + kkt;
      float dden = 1.0f - 2.0f * qk + qq * kkt;
      float num2 = Af * Af * qq + Bq * Bq * kkt - 2.0f * Af * Bq * qk;
      num2 = fmaxf(num2, 0.0f);
      float ad = fmaxf(fabsf(dden), 1e-12f);
      float n = sqrtf(num2) * __builtin_amdgcn_rcpf(ad);
      float sn = fminf(n, CLIP_HI);            // n >= 0 already
      // w = exp(-2*atanh(sn)/sqrt(dh)) = 2^(-invsqrtdh * (log2(1+sn)-log2(1-sn)))
      float L = fast_log2(1.0f + sn) - fast_log2(1.0f - sn);
      float w = fast_exp2(-INV_SQRT_DH * L);
      den += w;
      const float* vr = &Vs[tt * 32];
#pragma unroll
      for (int i = 0; i < 8; ++i) {
        float4 vv = *(const float4*)&vr[i * 4];
        acc[i * 4 + 0] = fmaf(w, vv.x, acc[i * 4 + 0]);
        acc[i * 4 + 1] = fmaf(w, vv.y, acc[i * 4 + 1]);
        acc[i * 4 + 2] = fmaf(w, vv.z, acc[i * 4 + 2]);
        acc[i * 4 + 3] = fmaf(w, vv.w, acc[i * 4 + 3]);
      }
    }
  }
  size_t pb = (((size_t)tc * 16 + bh) * 2048 + s) * 32;
#pragma unroll
  for (int i = 0; i < 8; ++i) {
    float4 o;
    o.x = acc[i * 4 + 0]; o.y = acc[i * 4 + 1];
    o.z = acc[i * 4 + 2]; o.w = acc[i * 4 + 3];
    *(float4*)&PN[pb + i * 4] = o;
  }
  PD[((size_t)tc * 16 + bh) * 2048 + s] = den;
}

// ---------------------------------------------------------------------------
// Sum the 4 t-chunk partials, normalize, write attention output in [B,S,D].
__global__ __launch_bounds__(256)
void combine(const float* __restrict__ PN, const float* __restrict__ PD,
             float* __restrict__ AO) {
  int idx = blockIdx.x * 256 + threadIdx.x;   // 0..32767 = (bh, s)
  int bh = idx >> 11, s = idx & 2047;
  int b = bh >> 3, h = bh & 7;
  float den = 0.0f;
#pragma unroll
  for (int c = 0; c < 4; ++c) den += PD[((size_t)c * 16 + bh) * 2048 + s];
  float r = 1.0f / den;                        // den >= ~236, safe
  size_t ob = ((size_t)b * 2048 + s) * 256 + h * 32;
#pragma unroll
  for (int i = 0; i < 8; ++i) {
    float4 sum = {0.0f, 0.0f, 0.0f, 0.0f};
#pragma unroll
    for (int c = 0; c < 4; ++c) {
      float4 v = *(const float4*)&PN[((((size_t)c * 16 + bh) * 2048 + s) * 32) + i * 4];
      sum.x += v.x; sum.y += v.y; sum.z += v.z; sum.w += v.w;
    }
    sum.x *= r; sum.y *= r; sum.z *= r; sum.w *= r;
    *(float4*)&AO[ob + i * 4] = sum;
  }
}

// ---------------------------------------------------------------------------
extern "C" void kernel_launch(void* const* d_in, const int* in_sizes, int n_in,
                              void* d_out, int out_size, void* d_ws, size_t ws_size,
                              hipStream_t stream) {
  const float* x   = (const float*)d_in[0];
  const float* Wq  = (const float*)d_in[1];
  const float* bq  = (const float*)d_in[2];
  const float* Wk  = (const float*)d_in[3];
  const float* bk  = (const float*)d_in[4];
  const float* Wv  = (const float*)d_in[5];
  const float* bv  = (const float*)d_in[6];
  const float* Wo  = (const float*)d_in[7];
  const float* bo  = (const float*)d_in[8];
  const float* Wfc = (const float*)d_in[9];
  const float* bfc = (const float*)d_in[10];

  float* ws = (float*)d_ws;
  // Workspace layout (floats). Total ~7.4M floats = 29.6 MB.
  float* Qb = ws;                       // [16][2048][32] = 1M
  float* Kb = ws + (1 << 20);           // 1M
  float* Vb = ws + (2 << 20);           // 1M
  float* QQ = ws + (3 << 20);           // 32768
  float* KK = QQ + 32768;               // 32768
  float* PN = KK + 32768;               // [4][16][2048][32] = 4M
  float* PD = PN + (4 << 20);           // [4][16][2048] = 131072
  float* AO = Kb;                       // reuse K region (dead after attn_part)
  float* T1 = Qb;                       // reuse Q region (dead after attn_part)

  dim3 blk(256);
  gemm_nt<1><<<dim3(64, 4), blk, 0, stream>>>(x, Wq, bq, Qb);
  gemm_nt<1><<<dim3(64, 4), blk, 0, stream>>>(x, Wk, bk, Kb);
  gemm_nt<1><<<dim3(64, 4), blk, 0, stream>>>(x, Wv, bv, Vb);
  expmap_qk<<<dim3(256), blk, 0, stream>>>(Qb, Kb, QQ, KK);
  attn_part<<<dim3(8, 4, 16), blk, 0, stream>>>(Qb, Kb, Vb, QQ, KK, PN, PD);
  combine<<<dim3(128), blk, 0, stream>>>(PN, PD, AO);
  gemm_nt<0><<<dim3(64, 4), blk, 0, stream>>>(AO, Wo, bo, T1);
  gemm_nt<0><<<dim3(64, 4), blk, 0, stream>>>(T1, Wfc, bfc, (float*)d_out);
}

// Round 3
// 358.231 us; speedup vs baseline: 1.3138x; 1.3138x over previous
//
#include <hip/hip_runtime.h>
#include <cstdint>
#include <cstddef>

// Poincare-ball (hyperbolic) attention block, fp32, occupancy-tuned.
// B=2, S=2048, D=256, H=8, dh=32, c=1.
//
// Round-2 -> Round-3 change: attn_part t-chunks 4 -> 8 (512 -> 1024 blocks,
// 2 -> 4 blocks/CU; LDS 33 KB/block allows exactly 4). Guarded by ws_size
// (needs 47.4 MB for the 8-chunk partial buffers; falls back to 4 chunks).

#define INV_SQRT_DH 0.17677669529663687f  // 1/sqrt(32)
#define CLIP_HI 0.99999f                  // 1 - 1e-5

__device__ __forceinline__ float fast_log2(float x) { return __builtin_amdgcn_logf(x); }
__device__ __forceinline__ float fast_exp2(float x) { return __builtin_amdgcn_exp2f(x); }

// ---------------------------------------------------------------------------
// fp32 GEMM: C[M=4096, N=256] = A[4096,256] @ W[256,256]^T + bias
// 64x64 tile, BK=32, 256 threads, 4x4 micro-tile.
// OUTMODE 0: row-major C[m*256+n].  OUTMODE 1: head-major Q[bh][s][dh].
template<int OUTMODE>
__global__ __launch_bounds__(256)
void gemm_nt(const float* __restrict__ A, const float* __restrict__ W,
             const float* __restrict__ bias, float* __restrict__ C) {
  __shared__ float As[64][36];
  __shared__ float Ws[64][36];
  const int tid = threadIdx.x;
  const int m0 = blockIdx.x * 64;
  const int n0 = blockIdx.y * 64;
  const int ty = tid >> 4, tx = tid & 15;
  float acc[4][4] = {};
  for (int k0 = 0; k0 < 256; k0 += 32) {
#pragma unroll
    for (int jj = 0; jj < 2; ++jj) {
      int j = tid * 2 + jj;          // 512 float4 per tile
      int r = j >> 3, c4 = (j & 7) << 2;
      *(float4*)&As[r][c4] = *(const float4*)&A[(size_t)(m0 + r) * 256 + k0 + c4];
      *(float4*)&Ws[r][c4] = *(const float4*)&W[(size_t)(n0 + r) * 256 + k0 + c4];
    }
    __syncthreads();
#pragma unroll
    for (int kk = 0; kk < 32; ++kk) {
      float a[4], b[4];
#pragma unroll
      for (int i = 0; i < 4; ++i) a[i] = As[ty * 4 + i][kk];
#pragma unroll
      for (int j = 0; j < 4; ++j) b[j] = Ws[tx * 4 + j][kk];
#pragma unroll
      for (int i = 0; i < 4; ++i)
#pragma unroll
        for (int j = 0; j < 4; ++j)
          acc[i][j] = fmaf(a[i], b[j], acc[i][j]);
    }
    __syncthreads();
  }
#pragma unroll
  for (int i = 0; i < 4; ++i) {
    int m = m0 + ty * 4 + i;
    float4 o;
    o.x = acc[i][0] + bias[n0 + tx * 4 + 0];
    o.y = acc[i][1] + bias[n0 + tx * 4 + 1];
    o.z = acc[i][2] + bias[n0 + tx * 4 + 2];
    o.w = acc[i][3] + bias[n0 + tx * 4 + 3];
    if (OUTMODE == 0) {
      *(float4*)&C[(size_t)m * 256 + n0 + tx * 4] = o;
    } else {
      int n = n0 + tx * 4;          // 4 cols stay within one head
      int h = n >> 5, d = n & 31;
      int b = m >> 11, s = m & 2047;
      *(float4*)&C[((size_t)((b << 3) + h) << 16) + (size_t)s * 32 + d] = o;
    }
  }
}

// ---------------------------------------------------------------------------
// expmap0 at origin on each dh=32 vector of Q and K (in place) + store |.|^2.
__global__ __launch_bounds__(256)
void expmap_qk(float* __restrict__ Q, float* __restrict__ K,
               float* __restrict__ QQ, float* __restrict__ KK) {
  int idx = blockIdx.x * 256 + threadIdx.x;   // 0..65535
  float* base;
  float* qqout;
  if (idx < 32768) { base = Q + (size_t)idx * 32; qqout = QQ + idx; }
  else             { int i2 = idx - 32768; base = K + (size_t)i2 * 32; qqout = KK + i2; }
  float4 v[8];
  float ss = 0.0f;
#pragma unroll
  for (int i = 0; i < 8; ++i) {
    v[i] = *(const float4*)&base[i * 4];
    ss = fmaf(v[i].x, v[i].x, ss);
    ss = fmaf(v[i].y, v[i].y, ss);
    ss = fmaf(v[i].z, v[i].z, ss);
    ss = fmaf(v[i].w, v[i].w, ss);
  }
  ss = fmaxf(ss, 1e-12f);
  float norm = sqrtf(ss);
  float t = tanhf(norm);
  float sc = t / norm;
#pragma unroll
  for (int i = 0; i < 8; ++i) {
    v[i].x *= sc; v[i].y *= sc; v[i].z *= sc; v[i].w *= sc;
    *(float4*)&base[i * 4] = v[i];
  }
  *qqout = t * t;
}

// ---------------------------------------------------------------------------
// Attention partial: thread = one q row; block = 256 q rows of one bh and
// S/NCHUNK t values (staged 128 at a time in LDS).
template<int NCHUNK>
__global__ __launch_bounds__(256)
void attn_part(const float* __restrict__ Q, const float* __restrict__ Kb,
               const float* __restrict__ Vb, const float* __restrict__ QQ,
               const float* __restrict__ KKa,
               float* __restrict__ PN, float* __restrict__ PD) {
  __shared__ float Ks[128 * 32];
  __shared__ float Vs[128 * 32];
  __shared__ float kks[128];
  const int tid = threadIdx.x;
  const int bh = blockIdx.z;                   // 0..15
  const int s  = blockIdx.x * 256 + tid;       // q row in [0,2048)
  const int tc = blockIdx.y;                   // t-chunk 0..NCHUNK-1
  const int TSPAN = 2048 / NCHUNK;

  const float* qrow = Q + ((size_t)bh << 16) + (size_t)s * 32;
  float q[32];
#pragma unroll
  for (int i = 0; i < 8; ++i) {
    float4 v4 = *(const float4*)&qrow[i * 4];
    q[i * 4 + 0] = v4.x; q[i * 4 + 1] = v4.y;
    q[i * 4 + 2] = v4.z; q[i * 4 + 3] = v4.w;
  }
  const float qq  = QQ[bh * 2048 + s];
  const float Bq  = 1.0f - qq;
  const float Bq2 = Bq * Bq;
  float acc[32] = {};
  float den = 0.0f;
  const float* Kp = Kb + ((size_t)bh << 16);
  const float* Vp = Vb + ((size_t)bh << 16);
  const float* kkp = KKa + bh * 2048;
  const int t0c = tc * TSPAN;

  for (int t0 = t0c; t0 < t0c + TSPAN; t0 += 128) {
    __syncthreads();
#pragma unroll
    for (int u = 0; u < 4; ++u) {
      int j = u * 256 + tid;                   // float4 index 0..1023
      *(float4*)&Ks[j * 4] = *(const float4*)&Kp[(size_t)t0 * 32 + j * 4];
      *(float4*)&Vs[j * 4] = *(const float4*)&Vp[(size_t)t0 * 32 + j * 4];
    }
    if (tid < 128) kks[tid] = kkp[t0 + tid];
    __syncthreads();

    for (int tt = 0; tt < 128; ++tt) {
      const float* kr = &Ks[tt * 32];
      float qk = 0.0f;
#pragma unroll
      for (int i = 0; i < 8; ++i) {
        float4 kv = *(const float4*)&kr[i * 4];
        qk = fmaf(q[i * 4 + 0], kv.x, qk);
        qk = fmaf(q[i * 4 + 1], kv.y, qk);
        qk = fmaf(q[i * 4 + 2], kv.z, qk);
        qk = fmaf(q[i * 4 + 3], kv.w, qk);
      }
      float kkt = kks[tt];
      float qk2 = qk + qk;
      // c = 1 closed-form Mobius-add norm (same math as reference, refactored)
      float Af   = (1.0f + kkt) - qk2;                 // 1 - 2qk + kk
      float dden = fmaf(qq, kkt, 1.0f) - qk2;          // 1 - 2qk + qq*kk
      float Bqk  = Bq * qk2;
      float t2   = fmaf(Af, qq, -Bqk);                 // A*qq - 2*Bq*qk
      float num2 = fmaf(Af, t2, Bq2 * kkt);            // A^2 qq - 2 A Bq qk + Bq^2 kk
      num2 = fmaxf(num2, 0.0f);
      float ad = fmaxf(fabsf(dden), 1e-12f);
      float n = sqrtf(num2) * __builtin_amdgcn_rcpf(ad);
      float sn = fminf(n, CLIP_HI);
      // w = exp(-2*atanh(sn)/sqrt(dh)) = 2^(-invsqrtdh*(log2(1+sn)-log2(1-sn)))
      float L = fast_log2(1.0f + sn) - fast_log2(1.0f - sn);
      float w = fast_exp2(-INV_SQRT_DH * L);
      den += w;
      const float* vr = &Vs[tt * 32];
#pragma unroll
      for (int i = 0; i < 8; ++i) {
        float4 vv = *(const float4*)&vr[i * 4];
        acc[i * 4 + 0] = fmaf(w, vv.x, acc[i * 4 + 0]);
        acc[i * 4 + 1] = fmaf(w, vv.y, acc[i * 4 + 1]);
        acc[i * 4 + 2] = fmaf(w, vv.z, acc[i * 4 + 2]);
        acc[i * 4 + 3] = fmaf(w, vv.w, acc[i * 4 + 3]);
      }
    }
  }
  size_t pb = (((size_t)tc * 16 + bh) * 2048 + s) * 32;
#pragma unroll
  for (int i = 0; i < 8; ++i) {
    float4 o;
    o.x = acc[i * 4 + 0]; o.y = acc[i * 4 + 1];
    o.z = acc[i * 4 + 2]; o.w = acc[i * 4 + 3];
    *(float4*)&PN[pb + i * 4] = o;
  }
  PD[((size_t)tc * 16 + bh) * 2048 + s] = den;
}

// ---------------------------------------------------------------------------
// Sum the NCHUNK t-chunk partials, normalize, write attention out in [B,S,D].
template<int NCHUNK>
__global__ __launch_bounds__(256)
void combine(const float* __restrict__ PN, const float* __restrict__ PD,
             float* __restrict__ AO) {
  int idx = blockIdx.x * 256 + threadIdx.x;   // 0..32767 = (bh, s)
  int bh = idx >> 11, s = idx & 2047;
  int b = bh >> 3, h = bh & 7;
  float den = 0.0f;
#pragma unroll
  for (int c = 0; c < NCHUNK; ++c) den += PD[((size_t)c * 16 + bh) * 2048 + s];
  float r = 1.0f / den;                        // den >= ~236, safe
  size_t ob = ((size_t)b * 2048 + s) * 256 + h * 32;
#pragma unroll
  for (int i = 0; i < 8; ++i) {
    float4 sum = {0.0f, 0.0f, 0.0f, 0.0f};
#pragma unroll
    for (int c = 0; c < NCHUNK; ++c) {
      float4 v = *(const float4*)&PN[((((size_t)c * 16 + bh) * 2048 + s) * 32) + i * 4];
      sum.x += v.x; sum.y += v.y; sum.z += v.z; sum.w += v.w;
    }
    sum.x *= r; sum.y *= r; sum.z *= r; sum.w *= r;
    *(float4*)&AO[ob + i * 4] = sum;
  }
}

// ---------------------------------------------------------------------------
extern "C" void kernel_launch(void* const* d_in, const int* in_sizes, int n_in,
                              void* d_out, int out_size, void* d_ws, size_t ws_size,
                              hipStream_t stream) {
  const float* x   = (const float*)d_in[0];
  const float* Wq  = (const float*)d_in[1];
  const float* bq  = (const float*)d_in[2];
  const float* Wk  = (const float*)d_in[3];
  const float* bk  = (const float*)d_in[4];
  const float* Wv  = (const float*)d_in[5];
  const float* bv  = (const float*)d_in[6];
  const float* Wo  = (const float*)d_in[7];
  const float* bo  = (const float*)d_in[8];
  const float* Wfc = (const float*)d_in[9];
  const float* bfc = (const float*)d_in[10];

  float* ws = (float*)d_ws;
  // Workspace layout (floats).
  float* Qb = ws;                       // [16][2048][32] = 1M
  float* Kb = ws + (1 << 20);           // 1M
  float* Vb = ws + (2 << 20);           // 1M
  float* QQ = ws + (3 << 20);           // 32768
  float* KK = QQ + 32768;               // 32768
  float* PN = KK + 32768;               // [NCHUNK][16][2048][32]
  float* AO = Kb;                       // reuse K region (dead after attn_part)
  float* T1 = Qb;                       // reuse Q region (dead after attn_part)

  dim3 blk(256);
  gemm_nt<1><<<dim3(64, 4), blk, 0, stream>>>(x, Wq, bq, Qb);
  gemm_nt<1><<<dim3(64, 4), blk, 0, stream>>>(x, Wk, bk, Kb);
  gemm_nt<1><<<dim3(64, 4), blk, 0, stream>>>(x, Wv, bv, Vb);
  expmap_qk<<<dim3(256), blk, 0, stream>>>(Qb, Kb, QQ, KK);

  // 8 t-chunks needs PN of 8*16*2048*32 floats (+PD): total 47.45 MB of ws.
  const size_t need8 = ((size_t)(3 << 20) + 65536 + (size_t)8 * (1 << 20) + 8 * 16 * 2048) * 4;
  if (ws_size >= need8) {
    float* PD = PN + ((size_t)8 << 20);
    attn_part<8><<<dim3(8, 8, 16), blk, 0, stream>>>(Qb, Kb, Vb, QQ, KK, PN, PD);
    combine<8><<<dim3(128), blk, 0, stream>>>(PN, PD, AO);
  } else {
    float* PD = PN + ((size_t)4 << 20);
    attn_part<4><<<dim3(8, 4, 16), blk, 0, stream>>>(Qb, Kb, Vb, QQ, KK, PN, PD);
    combine<4><<<dim3(128), blk, 0, stream>>>(PN, PD, AO);
  }
  gemm_nt<0><<<dim3(64, 4), blk, 0, stream>>>(AO, Wo, bo, T1);
  gemm_nt<0><<<dim3(64, 4), blk, 0, stream>>>(T1, Wfc, bfc, (float*)d_out);
}

// Round 4
// 251.031 us; speedup vs baseline: 1.8748x; 1.4270x over previous
//
#include <hip/hip_runtime.h>
#include <cstdint>
#include <cstddef>

// Poincare-ball (hyperbolic) attention block. B=2, S=2048, D=256, H=8, dh=32, c=1.
//
// Pipeline:
//   1) gemm_nt<1> x3 : Q/K/V = x @ W^T + b, fp32 head-major [bh][s][32]
//   2) prep_qk       : expmap0 -> bf16 Q/K + per-row (qq, a*log2(Bq)) tables
//   3) prep_vt       : V -> bf16 V^T [bh][dh][t]
//   4) attn_mfma     : flash-style: S^T = mfma(K,Q); w = exp2(max(aLgBq+aLgBk
//                      - a*log2(u+d+2*sqrt(u*d)), -3.11297)); O += mfma(P,V^T)
//                      using identity n^2 = u/d, u=qq+kk-2qk, d=1+qq*kk-2qk,
//                      d-u = (1-qq)(1-kk); scores bounded -> plain sum softmax.
//   5) gemm_nt<0> x2 : @ Wo^T + bo, then @ Wfc^T + bfc -> d_out

#define ALPHA 0.17677669529663687f   // 1/sqrt(32)
#define EMIN  -3.1129694f            // -ALPHA * log2((2-1e-5)/1e-5)  (clip)

typedef __bf16 bf16x8 __attribute__((ext_vector_type(8)));
typedef float  f32x4  __attribute__((ext_vector_type(4)));

__device__ __forceinline__ float fast_log2(float x) { return __builtin_amdgcn_logf(x); }
__device__ __forceinline__ float fast_exp2(float x) { return __builtin_amdgcn_exp2f(x); }

// ---------------------------------------------------------------------------
// fp32 GEMM: C[M=4096, N=256] = A[4096,256] @ W[256,256]^T + bias
// OUTMODE 0: row-major C[m*256+n].  OUTMODE 1: head-major Q[bh][s][dh].
template<int OUTMODE>
__global__ __launch_bounds__(256)
void gemm_nt(const float* __restrict__ A, const float* __restrict__ W,
             const float* __restrict__ bias, float* __restrict__ C) {
  __shared__ float As[64][36];
  __shared__ float Ws[64][36];
  const int tid = threadIdx.x;
  const int m0 = blockIdx.x * 64;
  const int n0 = blockIdx.y * 64;
  const int ty = tid >> 4, tx = tid & 15;
  float acc[4][4] = {};
  for (int k0 = 0; k0 < 256; k0 += 32) {
#pragma unroll
    for (int jj = 0; jj < 2; ++jj) {
      int j = tid * 2 + jj;
      int r = j >> 3, c4 = (j & 7) << 2;
      *(float4*)&As[r][c4] = *(const float4*)&A[(size_t)(m0 + r) * 256 + k0 + c4];
      *(float4*)&Ws[r][c4] = *(const float4*)&W[(size_t)(n0 + r) * 256 + k0 + c4];
    }
    __syncthreads();
#pragma unroll
    for (int kk = 0; kk < 32; ++kk) {
      float a[4], b[4];
#pragma unroll
      for (int i = 0; i < 4; ++i) a[i] = As[ty * 4 + i][kk];
#pragma unroll
      for (int j = 0; j < 4; ++j) b[j] = Ws[tx * 4 + j][kk];
#pragma unroll
      for (int i = 0; i < 4; ++i)
#pragma unroll
        for (int j = 0; j < 4; ++j)
          acc[i][j] = fmaf(a[i], b[j], acc[i][j]);
    }
    __syncthreads();
  }
#pragma unroll
  for (int i = 0; i < 4; ++i) {
    int m = m0 + ty * 4 + i;
    float4 o;
    o.x = acc[i][0] + bias[n0 + tx * 4 + 0];
    o.y = acc[i][1] + bias[n0 + tx * 4 + 1];
    o.z = acc[i][2] + bias[n0 + tx * 4 + 2];
    o.w = acc[i][3] + bias[n0 + tx * 4 + 3];
    if (OUTMODE == 0) {
      *(float4*)&C[(size_t)m * 256 + n0 + tx * 4] = o;
    } else {
      int n = n0 + tx * 4;
      int h = n >> 5, d = n & 31;
      int b = m >> 11, s = m & 2047;
      *(float4*)&C[((size_t)((b << 3) + h) << 16) + (size_t)s * 32 + d] = o;
    }
  }
}

// ---------------------------------------------------------------------------
// expmap0 on Q,K rows -> bf16 rows + (qq, ALPHA*log2(1-qq)) via sech^2 path.
__global__ __launch_bounds__(256)
void prep_qk(const float* __restrict__ Qf, const float* __restrict__ Kf,
             __bf16* __restrict__ Qbf, __bf16* __restrict__ Kbf,
             float2* __restrict__ qtab, float2* __restrict__ ktab) {
  int idx = blockIdx.x * 256 + threadIdx.x;   // 0..65535
  const float* src;
  __bf16* dst;
  float2* tab;
  if (idx < 32768) { src = Qf + (size_t)idx * 32; dst = Qbf + (size_t)idx * 32; tab = qtab + idx; }
  else { int i2 = idx - 32768; src = Kf + (size_t)i2 * 32; dst = Kbf + (size_t)i2 * 32; tab = ktab + i2; }
  float v[32];
  float ss = 0.0f;
#pragma unroll
  for (int i = 0; i < 8; ++i) {
    float4 v4 = *(const float4*)&src[i * 4];
    v[i*4+0] = v4.x; v[i*4+1] = v4.y; v[i*4+2] = v4.z; v[i*4+3] = v4.w;
    ss = fmaf(v4.x, v4.x, ss); ss = fmaf(v4.y, v4.y, ss);
    ss = fmaf(v4.z, v4.z, ss); ss = fmaf(v4.w, v4.w, ss);
  }
  ss = fmaxf(ss, 1e-12f);
  float x  = sqrtf(ss);
  // ex = e^{-2x}; tanh = (1-ex)/(1+ex); B = 1-tanh^2 = 4 ex/(1+ex)^2 (no cancel)
  float ex = fast_exp2(-2.8853900817779268f * x);       // 2*log2(e)*x
  float opex = 1.0f + ex;
  float th = (1.0f - ex) / opex;
  float sc = th / x;
  float qq = th * th;
  float lgB = 2.0f - 2.8853900817779268f * x - 2.0f * fast_log2(opex);
  *tab = float2{qq, ALPHA * lgB};
  union { __bf16 h[8]; uint4 u; } pk;
#pragma unroll
  for (int blk = 0; blk < 4; ++blk) {
#pragma unroll
    for (int j = 0; j < 8; ++j) pk.h[j] = (__bf16)(v[blk * 8 + j] * sc);
    *(uint4*)(dst + blk * 8) = pk.u;
  }
}

// ---------------------------------------------------------------------------
// V[bh][t][dh] fp32 -> V^T[bh][dh][t] bf16.
__global__ __launch_bounds__(256)
void prep_vt(const float* __restrict__ Vf, __bf16* __restrict__ Vt) {
  int g = blockIdx.x * 256 + threadIdx.x;     // 0..131071
  int bh = g >> 13, rem = g & 8191;
  int tb = rem >> 5, dh = rem & 31;
  const float* src = Vf + (((size_t)bh * 2048 + tb * 8) * 32) + dh;
  union { __bf16 h[8]; uint4 u; } pk;
#pragma unroll
  for (int e = 0; e < 8; ++e) pk.h[e] = (__bf16)src[e * 32];
  *(uint4*)(Vt + ((size_t)bh * 32 + dh) * 2048 + tb * 8) = pk.u;
}

// ---------------------------------------------------------------------------
// Flash attention with MFMA. Block: 4 waves; wave owns 16 q-rows (s = s0+lane&15),
// iterates t in 64-tiles. S^T = mfma(Kfrag, Qfrag) so lane's col is its s.
__global__ __launch_bounds__(256)
void attn_mfma(const __bf16* __restrict__ Qbf, const __bf16* __restrict__ Kbf,
               const __bf16* __restrict__ Vt,  const float2* __restrict__ qtab,
               const float2* __restrict__ ktab, float* __restrict__ AO) {
  __shared__ __bf16 Pt[4][16][72];   // per-wave P^T buffer, pitch 72 (144B, 16B-aligned rows)
  __shared__ float denS[4][16];
  const int tid = threadIdx.x;
  const int wid = tid >> 6, lane = tid & 63;
  const int l15 = lane & 15, lg = lane >> 4;          // lg in 0..3
  const int bh = blockIdx.y;
  const int s0 = blockIdx.x * 64 + wid * 16;

  // Hoisted per-wave Q fragment (B-operand: col=s, k=dh) + per-s scalars
  bf16x8 qfrag = *(const bf16x8*)(Qbf + ((size_t)bh * 2048 + s0 + l15) * 32 + lg * 8);
  float2 qt = qtab[bh * 2048 + s0 + l15];
  const float qq = qt.x, aLgBq = qt.y;

  const __bf16* Kbase = Kbf + (size_t)bh * 2048 * 32;
  const __bf16* Vbase = Vt + (size_t)bh * 32 * 2048;
  const float2* kt = ktab + bh * 2048;
  __bf16* Pw = &Pt[wid][0][0];

  f32x4 accO0 = {0.f, 0.f, 0.f, 0.f};
  f32x4 accO1 = {0.f, 0.f, 0.f, 0.f};
  float den = 0.0f;
  const f32x4 zero = {0.f, 0.f, 0.f, 0.f};

  for (int t0 = 0; t0 < 2048; t0 += 64) {
#pragma unroll
    for (int sub = 0; sub < 4; ++sub) {
      const int tt = t0 + sub * 16;
      // A-operand: K rows (m = t), contiguous 16B per lane
      bf16x8 kfrag = *(const bf16x8*)(Kbase + (size_t)(tt + l15) * 32 + lg * 8);
      // per-t scalars for this lane's 4 t-rows
      const int tk = tt + lg * 4;
      float4 kt01 = *(const float4*)&kt[tk];       // kk0 lg0 kk1 lg1
      float4 kt23 = *(const float4*)&kt[tk + 2];   // kk2 lg2 kk3 lg3
      f32x4 S = __builtin_amdgcn_mfma_f32_16x16x32_bf16(kfrag, qfrag, zero, 0, 0, 0);
      float kkv[4] = {kt01.x, kt01.z, kt23.x, kt23.z};
      float lbv[4] = {kt01.y, kt01.w, kt23.y, kt23.w};
      float w[4];
#pragma unroll
      for (int r = 0; r < 4; ++r) {
        float qk2 = S[r] + S[r];
        float u = (qq + kkv[r]) - qk2;             // ||q-k||^2
        float d = fmaf(qq, kkv[r], 1.0f) - qk2;    // Mobius denom (>0)
        float p = fmaxf(u * d, 0.0f);
        float sq = sqrtf(p);
        float m = fmaf(2.0f, sq, u + d);           // (sqrt d + sqrt u)^2
        float e = fmaf(-ALPHA, fast_log2(m), aLgBq + lbv[r]);
        e = fmaxf(e, EMIN);                        // == clip n <= 1-1e-5
        w[r] = fast_exp2(e);
      }
      den += (w[0] + w[1]) + (w[2] + w[3]);
      // write P^T: P[s=l15][t_local = sub*16 + lg*4 + r], 4 consecutive bf16
      union { __bf16 h[4]; uint2 u2; } pk;
      pk.h[0] = (__bf16)w[0]; pk.h[1] = (__bf16)w[1];
      pk.h[2] = (__bf16)w[2]; pk.h[3] = (__bf16)w[3];
      *(uint2*)&Pw[l15 * 72 + sub * 16 + lg * 4] = pk.u2;
    }
    // PV: O[s][dh] += P[s][t] * V[t][dh]  (wave-private LDS, no barrier needed)
#pragma unroll
    for (int th = 0; th < 2; ++th) {
      bf16x8 pfrag = *(const bf16x8*)&Pw[l15 * 72 + th * 32 + lg * 8];
      bf16x8 v0 = *(const bf16x8*)(Vbase + (size_t)(l15) * 2048 + t0 + th * 32 + lg * 8);
      bf16x8 v1 = *(const bf16x8*)(Vbase + (size_t)(16 + l15) * 2048 + t0 + th * 32 + lg * 8);
      accO0 = __builtin_amdgcn_mfma_f32_16x16x32_bf16(pfrag, v0, accO0, 0, 0, 0);
      accO1 = __builtin_amdgcn_mfma_f32_16x16x32_bf16(pfrag, v1, accO1, 0, 0, 0);
    }
  }
  // reduce den across the 4 lane-groups (same s lives in lanes l15, l15+16,+32,+48)
  den += __shfl_xor(den, 16);
  den += __shfl_xor(den, 32);
  if (lg == 0) denS[wid][l15] = den;
  // output: lane holds rows s_local = lg*4+r, col dh = l15 (+16 for accO1)
  int b = bh >> 3, h = bh & 7;
  float* aobase = AO + (size_t)b * 2048 * 256 + h * 32;
#pragma unroll
  for (int r = 0; r < 4; ++r) {
    int sl = lg * 4 + r;
    float rinv = 1.0f / denS[wid][sl];
    size_t row = (size_t)(s0 + sl) * 256;
    aobase[row + l15]      = accO0[r] * rinv;
    aobase[row + 16 + l15] = accO1[r] * rinv;
  }
}

// ---------------------------------------------------------------------------
extern "C" void kernel_launch(void* const* d_in, const int* in_sizes, int n_in,
                              void* d_out, int out_size, void* d_ws, size_t ws_size,
                              hipStream_t stream) {
  const float* x   = (const float*)d_in[0];
  const float* Wq  = (const float*)d_in[1];
  const float* bq  = (const float*)d_in[2];
  const float* Wk  = (const float*)d_in[3];
  const float* bk  = (const float*)d_in[4];
  const float* Wv  = (const float*)d_in[5];
  const float* bv  = (const float*)d_in[6];
  const float* Wo  = (const float*)d_in[7];
  const float* bo  = (const float*)d_in[8];
  const float* Wfc = (const float*)d_in[9];
  const float* bfc = (const float*)d_in[10];

  float* ws = (float*)d_ws;
  // Workspace layout (in floats):
  float* Qb  = ws;                         // [16][2048][32] fp32 = 1M
  float* Kb  = ws + (1 << 20);             // 1M
  float* Vb  = ws + (2 << 20);             // 1M
  __bf16* Qbf = (__bf16*)(ws + (3 << 20));            // 1M bf16 = .5M floats
  __bf16* Kbf = (__bf16*)(ws + (3 << 20) + (1 << 19)); // .5M floats
  __bf16* Vtb = (__bf16*)(ws + (4 << 20));            // .5M floats
  float2* qtab = (float2*)(ws + (4 << 20) + (1 << 19));          // 64K floats
  float2* ktab = (float2*)(ws + (4 << 20) + (1 << 19) + 65536);  // 64K floats
  float* AO = Qb;                          // reuse (Qb dead after prep_qk)
  float* T1 = Kb;                          // reuse (Kb dead after prep_qk)

  dim3 blk(256);
  gemm_nt<1><<<dim3(64, 4), blk, 0, stream>>>(x, Wq, bq, Qb);
  gemm_nt<1><<<dim3(64, 4), blk, 0, stream>>>(x, Wk, bk, Kb);
  gemm_nt<1><<<dim3(64, 4), blk, 0, stream>>>(x, Wv, bv, Vb);
  prep_qk<<<dim3(256), blk, 0, stream>>>(Qb, Kb, Qbf, Kbf, qtab, ktab);
  prep_vt<<<dim3(512), blk, 0, stream>>>(Vb, Vtb);
  attn_mfma<<<dim3(32, 16), blk, 0, stream>>>(Qbf, Kbf, Vtb, qtab, ktab, AO);
  gemm_nt<0><<<dim3(64, 4), blk, 0, stream>>>(AO, Wo, bo, T1);
  gemm_nt<0><<<dim3(64, 4), blk, 0, stream>>>(T1, Wfc, bfc, (float*)d_out);
}

// Round 5
// 149.033 us; speedup vs baseline: 3.1580x; 1.6844x over previous
//
#include <hip/hip_runtime.h>
#include <cstdint>
#include <cstddef>

// Poincare-ball (hyperbolic) attention block. B=2, S=2048, D=256, H=8, dh=32, c=1.
//
// Pipeline:
//   1) gemm_qkv   : fused Q/K/V = x @ W^T + b (one launch, 768 blocks), fp32,
//                   transposed-LDS inner loop (ds_read_b128), head-major out
//   2) prep_qk    : expmap0 -> bf16 Q/K + per-row (qq, a*log2(Bq)) tables
//   3) prep_vt    : V -> bf16 V^T [bh][dh][t]
//   4) wcomb/bcomb: Wcomb = Wfc@Wo, bcomb = Wfc@bo + bfc  (fold the two
//                   epilogue GEMMs into one)
//   5) attn_mfma  : t-split x4 flash: S^T = mfma(K,Q); w = exp2(max(aLgBk
//                   - a*log2(u+d+2*sqrt(u*d)), EMIN - aLgBq)); O += mfma(P,V^T)
//                   (per-row 2^-aLgBq scaling cancels in softmax)
//   6) combine    : sum 4 t-chunk partials, divide -> AO [B,S,D]
//   7) gemm64<0>  : out = AO @ Wcomb^T + bcomb

#define ALPHA 0.17677669529663687f   // 1/sqrt(32)
#define EMIN  -3.1129694f            // -ALPHA * log2((2-1e-5)/1e-5)  (clip)

typedef __bf16 bf16x8 __attribute__((ext_vector_type(8)));
typedef float  f32x4  __attribute__((ext_vector_type(4)));

__device__ __forceinline__ float fast_log2(float x) { return __builtin_amdgcn_logf(x); }
__device__ __forceinline__ float fast_exp2(float x) { return __builtin_amdgcn_exp2f(x); }

// ---------------------------------------------------------------------------
// Shared GEMM inner body: C_tile[64x64] += A[m0..][k] * W[n0..][k]^T.
// LDS tiles stored TRANSPOSED (AsT[kk][m]) so inner reads are ds_read_b128.
__device__ __forceinline__ void gemm_tile_nt(const float* __restrict__ A,
                                             const float* __restrict__ W,
                                             int m0, int n0,
                                             float (*AsT)[68], float (*WsT)[68],
                                             float acc[4][4]) {
  const int tid = threadIdx.x;
  const int ty = tid >> 4, tx = tid & 15;
  for (int k0 = 0; k0 < 256; k0 += 32) {
#pragma unroll
    for (int jj = 0; jj < 2; ++jj) {
      int j = tid * 2 + jj;            // 0..511
      int r = j >> 3;                  // 0..63 (m or n)
      int c4 = (j & 7) << 2;           // 0..28 (k offset)
      float4 av = *(const float4*)&A[(size_t)(m0 + r) * 256 + k0 + c4];
      float4 wv = *(const float4*)&W[(size_t)(n0 + r) * 256 + k0 + c4];
      AsT[c4 + 0][r] = av.x; AsT[c4 + 1][r] = av.y;
      AsT[c4 + 2][r] = av.z; AsT[c4 + 3][r] = av.w;
      WsT[c4 + 0][r] = wv.x; WsT[c4 + 1][r] = wv.y;
      WsT[c4 + 2][r] = wv.z; WsT[c4 + 3][r] = wv.w;
    }
    __syncthreads();
#pragma unroll
    for (int kk = 0; kk < 32; ++kk) {
      float4 a = *(const float4*)&AsT[kk][ty * 4];
      float4 b = *(const float4*)&WsT[kk][tx * 4];
      float av[4] = {a.x, a.y, a.z, a.w};
      float bv[4] = {b.x, b.y, b.z, b.w};
#pragma unroll
      for (int i = 0; i < 4; ++i)
#pragma unroll
        for (int j = 0; j < 4; ++j)
          acc[i][j] = fmaf(av[i], bv[j], acc[i][j]);
    }
    __syncthreads();
  }
}

// ---------------------------------------------------------------------------
// Fused QKV projection. Grid (64, 12): by>>2 selects {Q,K,V}, (by&3)*64 = n0.
// Output head-major [bh][s][32].
__global__ __launch_bounds__(256)
void gemm_qkv(const float* __restrict__ x,
              const float* __restrict__ Wq, const float* __restrict__ bq,
              const float* __restrict__ Wk, const float* __restrict__ bk,
              const float* __restrict__ Wv, const float* __restrict__ bv,
              float* __restrict__ Qb, float* __restrict__ Kb, float* __restrict__ Vb) {
  __shared__ float AsT[32][68];
  __shared__ float WsT[32][68];
  const int wsel = blockIdx.y >> 2;
  const float* W    = wsel == 0 ? Wq : (wsel == 1 ? Wk : Wv);
  const float* bias = wsel == 0 ? bq : (wsel == 1 ? bk : bv);
  float* C          = wsel == 0 ? Qb : (wsel == 1 ? Kb : Vb);
  const int m0 = blockIdx.x * 64;
  const int n0 = (blockIdx.y & 3) * 64;
  float acc[4][4] = {};
  gemm_tile_nt(x, W, m0, n0, AsT, WsT, acc);
  const int ty = threadIdx.x >> 4, tx = threadIdx.x & 15;
#pragma unroll
  for (int i = 0; i < 4; ++i) {
    int m = m0 + ty * 4 + i;
    float4 o;
    o.x = acc[i][0] + bias[n0 + tx * 4 + 0];
    o.y = acc[i][1] + bias[n0 + tx * 4 + 1];
    o.z = acc[i][2] + bias[n0 + tx * 4 + 2];
    o.w = acc[i][3] + bias[n0 + tx * 4 + 3];
    int n = n0 + tx * 4;                 // 4 cols stay within one head
    int h = n >> 5, d = n & 31;
    int b = m >> 11, s = m & 2047;
    *(float4*)&C[((size_t)((b << 3) + h) << 16) + (size_t)s * 32 + d] = o;
  }
}

// ---------------------------------------------------------------------------
// Plain NT GEMM (row-major out): C = A @ W^T + bias. Grid (M/64, N/64).
__global__ __launch_bounds__(256)
void gemm64(const float* __restrict__ A, const float* __restrict__ W,
            const float* __restrict__ bias, float* __restrict__ C, int ldc) {
  __shared__ float AsT[32][68];
  __shared__ float WsT[32][68];
  const int m0 = blockIdx.x * 64;
  const int n0 = blockIdx.y * 64;
  float acc[4][4] = {};
  gemm_tile_nt(A, W, m0, n0, AsT, WsT, acc);
  const int ty = threadIdx.x >> 4, tx = threadIdx.x & 15;
#pragma unroll
  for (int i = 0; i < 4; ++i) {
    int m = m0 + ty * 4 + i;
    float4 o;
    o.x = acc[i][0] + bias[n0 + tx * 4 + 0];
    o.y = acc[i][1] + bias[n0 + tx * 4 + 1];
    o.z = acc[i][2] + bias[n0 + tx * 4 + 2];
    o.w = acc[i][3] + bias[n0 + tx * 4 + 3];
    *(float4*)&C[(size_t)m * ldc + n0 + tx * 4] = o;
  }
}

// ---------------------------------------------------------------------------
// Wcomb = Wfc @ Wo (NN, 256x256x256). Grid (4,4).
__global__ __launch_bounds__(256)
void gemm_nn_small(const float* __restrict__ Afc, const float* __restrict__ Bo,
                   float* __restrict__ C) {
  __shared__ float AsT[32][68];
  __shared__ float Bs[32][68];
  const int tid = threadIdx.x;
  const int ty = tid >> 4, tx = tid & 15;
  const int m0 = blockIdx.x * 64;
  const int n0 = blockIdx.y * 64;
  float acc[4][4] = {};
  for (int k0 = 0; k0 < 256; k0 += 32) {
#pragma unroll
    for (int jj = 0; jj < 2; ++jj) {
      int j = tid * 2 + jj;            // 0..511
      { // A: rows m, transpose-store
        int r = j >> 3, c4 = (j & 7) << 2;
        float4 av = *(const float4*)&Afc[(size_t)(m0 + r) * 256 + k0 + c4];
        AsT[c4 + 0][r] = av.x; AsT[c4 + 1][r] = av.y;
        AsT[c4 + 2][r] = av.z; AsT[c4 + 3][r] = av.w;
      }
      { // B: rows k, direct store Bs[kk][n]
        int r = j >> 4, c4 = (j & 15) << 2;
        *(float4*)&Bs[r][c4] = *(const float4*)&Bo[(size_t)(k0 + r) * 256 + n0 + c4];
      }
    }
    __syncthreads();
#pragma unroll
    for (int kk = 0; kk < 32; ++kk) {
      float4 a = *(const float4*)&AsT[kk][ty * 4];
      float4 b = *(const float4*)&Bs[kk][tx * 4];
      float av[4] = {a.x, a.y, a.z, a.w};
      float bv[4] = {b.x, b.y, b.z, b.w};
#pragma unroll
      for (int i = 0; i < 4; ++i)
#pragma unroll
        for (int j2 = 0; j2 < 4; ++j2)
          acc[i][j2] = fmaf(av[i], bv[j2], acc[i][j2]);
    }
    __syncthreads();
  }
#pragma unroll
  for (int i = 0; i < 4; ++i) {
    float4 o = {acc[i][0], acc[i][1], acc[i][2], acc[i][3]};
    *(float4*)&C[(size_t)(m0 + ty * 4 + i) * 256 + n0 + tx * 4] = o;
  }
}

// ---------------------------------------------------------------------------
// bcomb = Wfc @ bo + bfc. Grid 16 blocks x 16 rows.
__global__ __launch_bounds__(256)
void bcomb_k(const float* __restrict__ Wfc, const float* __restrict__ bo,
             const float* __restrict__ bfc, float* __restrict__ bcomb) {
  __shared__ float red[256];
  int r = threadIdx.x >> 4, c = threadIdx.x & 15;
  int row = blockIdx.x * 16 + r;
  float s = 0.0f;
  for (int k = c; k < 256; k += 16) s = fmaf(Wfc[(size_t)row * 256 + k], bo[k], s);
  red[threadIdx.x] = s;
  __syncthreads();
  if (c == 0) {
    float t = 0.0f;
#pragma unroll
    for (int i = 0; i < 16; ++i) t += red[r * 16 + i];
    bcomb[row] = t + bfc[row];
  }
}

// ---------------------------------------------------------------------------
// expmap0 on Q,K rows -> bf16 rows + (qq, ALPHA*log2(1-qq)) via sech^2 path.
__global__ __launch_bounds__(256)
void prep_qk(const float* __restrict__ Qf, const float* __restrict__ Kf,
             __bf16* __restrict__ Qbf, __bf16* __restrict__ Kbf,
             float2* __restrict__ qtab, float2* __restrict__ ktab) {
  int idx = blockIdx.x * 256 + threadIdx.x;   // 0..65535
  const float* src;
  __bf16* dst;
  float2* tab;
  if (idx < 32768) { src = Qf + (size_t)idx * 32; dst = Qbf + (size_t)idx * 32; tab = qtab + idx; }
  else { int i2 = idx - 32768; src = Kf + (size_t)i2 * 32; dst = Kbf + (size_t)i2 * 32; tab = ktab + i2; }
  float v[32];
  float ss = 0.0f;
#pragma unroll
  for (int i = 0; i < 8; ++i) {
    float4 v4 = *(const float4*)&src[i * 4];
    v[i*4+0] = v4.x; v[i*4+1] = v4.y; v[i*4+2] = v4.z; v[i*4+3] = v4.w;
    ss = fmaf(v4.x, v4.x, ss); ss = fmaf(v4.y, v4.y, ss);
    ss = fmaf(v4.z, v4.z, ss); ss = fmaf(v4.w, v4.w, ss);
  }
  ss = fmaxf(ss, 1e-12f);
  float x  = sqrtf(ss);
  // ex = e^{-2x}; tanh = (1-ex)/(1+ex); B = 1-tanh^2 = 4 ex/(1+ex)^2 (no cancel)
  float ex = fast_exp2(-2.8853900817779268f * x);       // 2*log2(e)*x
  float opex = 1.0f + ex;
  float th = (1.0f - ex) / opex;
  float sc = th / x;
  float qq = th * th;
  float lgB = 2.0f - 2.8853900817779268f * x - 2.0f * fast_log2(opex);
  *tab = float2{qq, ALPHA * lgB};
  union { __bf16 h[8]; uint4 u; } pk;
#pragma unroll
  for (int blk = 0; blk < 4; ++blk) {
#pragma unroll
    for (int j = 0; j < 8; ++j) pk.h[j] = (__bf16)(v[blk * 8 + j] * sc);
    *(uint4*)(dst + blk * 8) = pk.u;
  }
}

// ---------------------------------------------------------------------------
// V[bh][t][dh] fp32 -> V^T[bh][dh][t] bf16.
__global__ __launch_bounds__(256)
void prep_vt(const float* __restrict__ Vf, __bf16* __restrict__ Vt) {
  int g = blockIdx.x * 256 + threadIdx.x;     // 0..131071
  int bh = g >> 13, rem = g & 8191;
  int tb = rem >> 5, dh = rem & 31;
  const float* src = Vf + (((size_t)bh * 2048 + tb * 8) * 32) + dh;
  union { __bf16 h[8]; uint4 u; } pk;
#pragma unroll
  for (int e = 0; e < 8; ++e) pk.h[e] = (__bf16)src[e * 32];
  *(uint4*)(Vt + ((size_t)bh * 32 + dh) * 2048 + tb * 8) = pk.u;
}

// ---------------------------------------------------------------------------
// Flash attention with MFMA, t-split. Block: 4 waves; wave owns 16 q-rows,
// covers t in [tc*512, tc*512+512). Grid (32, 4, 16).
__global__ __launch_bounds__(256)
void attn_mfma(const __bf16* __restrict__ Qbf, const __bf16* __restrict__ Kbf,
               const __bf16* __restrict__ Vt,  const float2* __restrict__ qtab,
               const float2* __restrict__ ktab,
               float* __restrict__ PN, float* __restrict__ PD) {
  __shared__ __bf16 Pt[4][16][72];   // per-wave P^T buffer, pitch 72
  const int tid = threadIdx.x;
  const int wid = tid >> 6, lane = tid & 63;
  const int l15 = lane & 15, lg = lane >> 4;          // lg in 0..3
  const int tc = blockIdx.y;                          // t-chunk 0..3
  const int bh = blockIdx.z;
  const int s0 = blockIdx.x * 64 + wid * 16;

  // Hoisted per-wave Q fragment (B-operand: col=s, k=dh) + per-s scalars
  bf16x8 qfrag = *(const bf16x8*)(Qbf + ((size_t)bh * 2048 + s0 + l15) * 32 + lg * 8);
  float2 qt = qtab[bh * 2048 + s0 + l15];
  const float qq = qt.x;
  const float eminRow = EMIN - qt.y;   // per-row clip floor (2^-aLgBq scaling cancels)

  const __bf16* Kbase = Kbf + (size_t)bh * 2048 * 32;
  const __bf16* Vbase = Vt + (size_t)bh * 32 * 2048;
  const float2* kt = ktab + bh * 2048;
  __bf16* Pw = &Pt[wid][0][0];

  f32x4 accO0 = {0.f, 0.f, 0.f, 0.f};
  f32x4 accO1 = {0.f, 0.f, 0.f, 0.f};
  float den = 0.0f;
  const f32x4 zero = {0.f, 0.f, 0.f, 0.f};

  const int tbeg = tc * 512;
  for (int t0 = tbeg; t0 < tbeg + 512; t0 += 64) {
#pragma unroll
    for (int sub = 0; sub < 4; ++sub) {
      const int tt = t0 + sub * 16;
      bf16x8 kfrag = *(const bf16x8*)(Kbase + (size_t)(tt + l15) * 32 + lg * 8);
      const int tk = tt + lg * 4;
      float4 kt01 = *(const float4*)&kt[tk];       // kk0 lg0 kk1 lg1
      float4 kt23 = *(const float4*)&kt[tk + 2];   // kk2 lg2 kk3 lg3
      f32x4 S = __builtin_amdgcn_mfma_f32_16x16x32_bf16(kfrag, qfrag, zero, 0, 0, 0);
      float kkv[4] = {kt01.x, kt01.z, kt23.x, kt23.z};
      float lbv[4] = {kt01.y, kt01.w, kt23.y, kt23.w};
      float w[4];
#pragma unroll
      for (int r = 0; r < 4; ++r) {
        float qk2 = S[r] + S[r];
        float u = (qq + kkv[r]) - qk2;             // ||q-k||^2
        float d = fmaf(qq, kkv[r], 1.0f) - qk2;    // Mobius denom (>0)
        float p = fmaxf(u * d, 0.0f);
        float sq = sqrtf(p);
        float m = fmaf(2.0f, sq, u + d);           // (sqrt d + sqrt u)^2
        float e = fmaf(-ALPHA, fast_log2(m), lbv[r]);
        e = fmaxf(e, eminRow);                     // == clip n <= 1-1e-5
        w[r] = fast_exp2(e);
      }
      den += (w[0] + w[1]) + (w[2] + w[3]);
      union { __bf16 h[4]; uint2 u2; } pk;
      pk.h[0] = (__bf16)w[0]; pk.h[1] = (__bf16)w[1];
      pk.h[2] = (__bf16)w[2]; pk.h[3] = (__bf16)w[3];
      *(uint2*)&Pw[l15 * 72 + sub * 16 + lg * 4] = pk.u2;
    }
    // PV: O[s][dh] += P[s][t] * V[t][dh]  (wave-private LDS, no barrier)
#pragma unroll
    for (int th = 0; th < 2; ++th) {
      bf16x8 pfrag = *(const bf16x8*)&Pw[l15 * 72 + th * 32 + lg * 8];
      bf16x8 v0 = *(const bf16x8*)(Vbase + (size_t)(l15) * 2048 + t0 + th * 32 + lg * 8);
      bf16x8 v1 = *(const bf16x8*)(Vbase + (size_t)(16 + l15) * 2048 + t0 + th * 32 + lg * 8);
      accO0 = __builtin_amdgcn_mfma_f32_16x16x32_bf16(pfrag, v0, accO0, 0, 0, 0);
      accO1 = __builtin_amdgcn_mfma_f32_16x16x32_bf16(pfrag, v1, accO1, 0, 0, 0);
    }
  }
  // den lives replicated in lg groups; reduce and store once
  den += __shfl_xor(den, 16);
  den += __shfl_xor(den, 32);
  size_t pbase = ((size_t)tc * 16 + bh) * 2048;
  if (lg == 0) PD[pbase + s0 + l15] = den;
  // partial O: lane holds rows sl = lg*4+r, col dh = l15 (+16 for accO1)
#pragma unroll
  for (int r = 0; r < 4; ++r) {
    int sl = lg * 4 + r;
    size_t row = (pbase + s0 + sl) * 32;
    PN[row + l15]      = accO0[r];
    PN[row + 16 + l15] = accO1[r];
  }
}

// ---------------------------------------------------------------------------
// Sum the 4 t-chunk partials, normalize, write attention out in [B,S,D].
__global__ __launch_bounds__(256)
void combine4(const float* __restrict__ PN, const float* __restrict__ PD,
              float* __restrict__ AO) {
  int idx = blockIdx.x * 256 + threadIdx.x;   // 0..32767 = (bh, s)
  int bh = idx >> 11, s = idx & 2047;
  int b = bh >> 3, h = bh & 7;
  float den = 0.0f;
#pragma unroll
  for (int c = 0; c < 4; ++c) den += PD[((size_t)c * 16 + bh) * 2048 + s];
  float r = 1.0f / den;
  size_t ob = ((size_t)b * 2048 + s) * 256 + h * 32;
#pragma unroll
  for (int i = 0; i < 8; ++i) {
    float4 sum = {0.0f, 0.0f, 0.0f, 0.0f};
#pragma unroll
    for (int c = 0; c < 4; ++c) {
      float4 v = *(const float4*)&PN[((((size_t)c * 16 + bh) * 2048 + s) * 32) + i * 4];
      sum.x += v.x; sum.y += v.y; sum.z += v.z; sum.w += v.w;
    }
    sum.x *= r; sum.y *= r; sum.z *= r; sum.w *= r;
    *(float4*)&AO[ob + i * 4] = sum;
  }
}

// ---------------------------------------------------------------------------
extern "C" void kernel_launch(void* const* d_in, const int* in_sizes, int n_in,
                              void* d_out, int out_size, void* d_ws, size_t ws_size,
                              hipStream_t stream) {
  const float* x   = (const float*)d_in[0];
  const float* Wq  = (const float*)d_in[1];
  const float* bq  = (const float*)d_in[2];
  const float* Wk  = (const float*)d_in[3];
  const float* bk  = (const float*)d_in[4];
  const float* Wv  = (const float*)d_in[5];
  const float* bv  = (const float*)d_in[6];
  const float* Wo  = (const float*)d_in[7];
  const float* bo  = (const float*)d_in[8];
  const float* Wfc = (const float*)d_in[9];
  const float* bfc = (const float*)d_in[10];

  float* ws = (float*)d_ws;
  // Workspace layout (floats); total ~9.13M floats = 36.5 MB.
  float* Qb  = ws;                                   // [16][2048][32] = 1M
  float* Kb  = ws + (1 << 20);                       // 1M
  float* Vb  = ws + (2 << 20);                       // 1M
  __bf16* Qbf = (__bf16*)(ws + (3 << 20));           // 1M bf16
  __bf16* Kbf = (__bf16*)(ws + (3 << 20) + (1 << 19));
  __bf16* Vtb = (__bf16*)(ws + (4 << 20));           // 1M bf16
  float2* qtab = (float2*)(ws + (4 << 20) + (1 << 19));            // 64K floats
  float2* ktab = (float2*)(ws + (4 << 20) + (1 << 19) + 65536);    // 64K floats
  float* Wcomb = ws + (4 << 20) + (1 << 19) + 2 * 65536;           // 64K floats
  float* bcomb = Wcomb + 65536;                                    // 256
  float* PN = ws + (5 << 20);                        // [4][16][2048][32] = 4M
  float* PD = ws + (9 << 20);                        // 128K
  float* AO = Qb;                                    // reuse (dead after prep_qk)

  dim3 blk(256);
  gemm_qkv<<<dim3(64, 12), blk, 0, stream>>>(x, Wq, bq, Wk, bk, Wv, bv, Qb, Kb, Vb);
  prep_qk<<<dim3(256), blk, 0, stream>>>(Qb, Kb, Qbf, Kbf, qtab, ktab);
  prep_vt<<<dim3(512), blk, 0, stream>>>(Vb, Vtb);
  gemm_nn_small<<<dim3(4, 4), blk, 0, stream>>>(Wfc, Wo, Wcomb);
  bcomb_k<<<dim3(16), blk, 0, stream>>>(Wfc, bo, bfc, bcomb);
  attn_mfma<<<dim3(32, 4, 16), blk, 0, stream>>>(Qbf, Kbf, Vtb, qtab, ktab, PN, PD);
  combine4<<<dim3(128), blk, 0, stream>>>(PN, PD, AO);
  gemm64<<<dim3(64, 4), blk, 0, stream>>>(AO, Wcomb, bcomb, (float*)d_out, 256);
}

// Round 6
// 146.763 us; speedup vs baseline: 3.2068x; 1.0155x over previous
//
#include <hip/hip_runtime.h>
#include <cstdint>
#include <cstddef>

// Poincare-ball (hyperbolic) attention block. B=2, S=2048, D=256, H=8, dh=32, c=1.
//
// Pipeline:
//   1) gemm_qkv   : fused Q/K/V = x @ W^T + b (one launch), fp32, transposed-LDS
//   2) prep_qk    : expmap0 -> bf16 Q/K + row tables (qq, a*log2 B, B)
//   3) prep_vt    : V -> bf16 V^T [bh][dh][t]
//   4) wcomb/bcomb: Wcomb = Wfc@Wo, bcomb = Wfc@bo + bfc (fold epilogue GEMMs)
//   5) attn_mfma  : t-split x4 flash, S^T = mfma(K,Q).
//                   FAST PATH: exact clip test BqBk <= chi*d (chi = 1-(1-1e-5)^2);
//                   when a whole 16-t subtile clips (the overwhelmingly common
//                   case for this data), w == 2^eminRow is lane-constant ->
//                   skip sqrt/log2/exp2 entirely. Slow path = exact full chain.
//   6) combine    : sum 4 t-chunk partials, divide -> AO [B,S,D]
//   7) gemm64     : out = AO @ Wcomb^T + bcomb

#define ALPHA 0.17677669529663687f   // 1/sqrt(32)
#define EMIN  -3.1129694f            // -ALPHA * log2((2-1e-5)/1e-5)  (clip)
#define CHI   1.95e-5f               // conservative 1-(1-1e-5)^2 (true: 1.99999e-5)

typedef __bf16 bf16x8 __attribute__((ext_vector_type(8)));
typedef float  f32x4  __attribute__((ext_vector_type(4)));

__device__ __forceinline__ float fast_log2(float x) { return __builtin_amdgcn_logf(x); }
__device__ __forceinline__ float fast_exp2(float x) { return __builtin_amdgcn_exp2f(x); }

// ---------------------------------------------------------------------------
// Shared GEMM inner body: C_tile[64x64] += A[m0..][k] * W[n0..][k]^T.
// LDS tiles stored TRANSPOSED (AsT[kk][m]) so inner reads are ds_read_b128.
__device__ __forceinline__ void gemm_tile_nt(const float* __restrict__ A,
                                             const float* __restrict__ W,
                                             int m0, int n0,
                                             float (*AsT)[68], float (*WsT)[68],
                                             float acc[4][4]) {
  const int tid = threadIdx.x;
  const int ty = tid >> 4, tx = tid & 15;
  for (int k0 = 0; k0 < 256; k0 += 32) {
#pragma unroll
    for (int jj = 0; jj < 2; ++jj) {
      int j = tid * 2 + jj;            // 0..511
      int r = j >> 3;                  // 0..63 (m or n)
      int c4 = (j & 7) << 2;           // 0..28 (k offset)
      float4 av = *(const float4*)&A[(size_t)(m0 + r) * 256 + k0 + c4];
      float4 wv = *(const float4*)&W[(size_t)(n0 + r) * 256 + k0 + c4];
      AsT[c4 + 0][r] = av.x; AsT[c4 + 1][r] = av.y;
      AsT[c4 + 2][r] = av.z; AsT[c4 + 3][r] = av.w;
      WsT[c4 + 0][r] = wv.x; WsT[c4 + 1][r] = wv.y;
      WsT[c4 + 2][r] = wv.z; WsT[c4 + 3][r] = wv.w;
    }
    __syncthreads();
#pragma unroll
    for (int kk = 0; kk < 32; ++kk) {
      float4 a = *(const float4*)&AsT[kk][ty * 4];
      float4 b = *(const float4*)&WsT[kk][tx * 4];
      float av[4] = {a.x, a.y, a.z, a.w};
      float bv[4] = {b.x, b.y, b.z, b.w};
#pragma unroll
      for (int i = 0; i < 4; ++i)
#pragma unroll
        for (int j = 0; j < 4; ++j)
          acc[i][j] = fmaf(av[i], bv[j], acc[i][j]);
    }
    __syncthreads();
  }
}

// ---------------------------------------------------------------------------
// Fused QKV projection. Grid (64, 12): by>>2 selects {Q,K,V}, (by&3)*64 = n0.
__global__ __launch_bounds__(256)
void gemm_qkv(const float* __restrict__ x,
              const float* __restrict__ Wq, const float* __restrict__ bq,
              const float* __restrict__ Wk, const float* __restrict__ bk,
              const float* __restrict__ Wv, const float* __restrict__ bv,
              float* __restrict__ Qb, float* __restrict__ Kb, float* __restrict__ Vb) {
  __shared__ float AsT[32][68];
  __shared__ float WsT[32][68];
  const int wsel = blockIdx.y >> 2;
  const float* W    = wsel == 0 ? Wq : (wsel == 1 ? Wk : Wv);
  const float* bias = wsel == 0 ? bq : (wsel == 1 ? bk : bv);
  float* C          = wsel == 0 ? Qb : (wsel == 1 ? Kb : Vb);
  const int m0 = blockIdx.x * 64;
  const int n0 = (blockIdx.y & 3) * 64;
  float acc[4][4] = {};
  gemm_tile_nt(x, W, m0, n0, AsT, WsT, acc);
  const int ty = threadIdx.x >> 4, tx = threadIdx.x & 15;
#pragma unroll
  for (int i = 0; i < 4; ++i) {
    int m = m0 + ty * 4 + i;
    float4 o;
    o.x = acc[i][0] + bias[n0 + tx * 4 + 0];
    o.y = acc[i][1] + bias[n0 + tx * 4 + 1];
    o.z = acc[i][2] + bias[n0 + tx * 4 + 2];
    o.w = acc[i][3] + bias[n0 + tx * 4 + 3];
    int n = n0 + tx * 4;
    int h = n >> 5, d = n & 31;
    int b = m >> 11, s = m & 2047;
    *(float4*)&C[((size_t)((b << 3) + h) << 16) + (size_t)s * 32 + d] = o;
  }
}

// ---------------------------------------------------------------------------
// Plain NT GEMM (row-major out): C = A @ W^T + bias. Grid (M/64, N/64).
__global__ __launch_bounds__(256)
void gemm64(const float* __restrict__ A, const float* __restrict__ W,
            const float* __restrict__ bias, float* __restrict__ C, int ldc) {
  __shared__ float AsT[32][68];
  __shared__ float WsT[32][68];
  const int m0 = blockIdx.x * 64;
  const int n0 = blockIdx.y * 64;
  float acc[4][4] = {};
  gemm_tile_nt(A, W, m0, n0, AsT, WsT, acc);
  const int ty = threadIdx.x >> 4, tx = threadIdx.x & 15;
#pragma unroll
  for (int i = 0; i < 4; ++i) {
    int m = m0 + ty * 4 + i;
    float4 o;
    o.x = acc[i][0] + bias[n0 + tx * 4 + 0];
    o.y = acc[i][1] + bias[n0 + tx * 4 + 1];
    o.z = acc[i][2] + bias[n0 + tx * 4 + 2];
    o.w = acc[i][3] + bias[n0 + tx * 4 + 3];
    *(float4*)&C[(size_t)m * ldc + n0 + tx * 4] = o;
  }
}

// ---------------------------------------------------------------------------
// Wcomb = Wfc @ Wo (NN, 256x256x256). Grid (4,4).
__global__ __launch_bounds__(256)
void gemm_nn_small(const float* __restrict__ Afc, const float* __restrict__ Bo,
                   float* __restrict__ C) {
  __shared__ float AsT[32][68];
  __shared__ float Bs[32][68];
  const int tid = threadIdx.x;
  const int ty = tid >> 4, tx = tid & 15;
  const int m0 = blockIdx.x * 64;
  const int n0 = blockIdx.y * 64;
  float acc[4][4] = {};
  for (int k0 = 0; k0 < 256; k0 += 32) {
#pragma unroll
    for (int jj = 0; jj < 2; ++jj) {
      int j = tid * 2 + jj;
      {
        int r = j >> 3, c4 = (j & 7) << 2;
        float4 av = *(const float4*)&Afc[(size_t)(m0 + r) * 256 + k0 + c4];
        AsT[c4 + 0][r] = av.x; AsT[c4 + 1][r] = av.y;
        AsT[c4 + 2][r] = av.z; AsT[c4 + 3][r] = av.w;
      }
      {
        int r = j >> 4, c4 = (j & 15) << 2;
        *(float4*)&Bs[r][c4] = *(const float4*)&Bo[(size_t)(k0 + r) * 256 + n0 + c4];
      }
    }
    __syncthreads();
#pragma unroll
    for (int kk = 0; kk < 32; ++kk) {
      float4 a = *(const float4*)&AsT[kk][ty * 4];
      float4 b = *(const float4*)&Bs[kk][tx * 4];
      float av[4] = {a.x, a.y, a.z, a.w};
      float bv[4] = {b.x, b.y, b.z, b.w};
#pragma unroll
      for (int i = 0; i < 4; ++i)
#pragma unroll
        for (int j2 = 0; j2 < 4; ++j2)
          acc[i][j2] = fmaf(av[i], bv[j2], acc[i][j2]);
    }
    __syncthreads();
  }
#pragma unroll
  for (int i = 0; i < 4; ++i) {
    float4 o = {acc[i][0], acc[i][1], acc[i][2], acc[i][3]};
    *(float4*)&C[(size_t)(m0 + ty * 4 + i) * 256 + n0 + tx * 4] = o;
  }
}

// ---------------------------------------------------------------------------
// bcomb = Wfc @ bo + bfc. Grid 16 blocks x 16 rows.
__global__ __launch_bounds__(256)
void bcomb_k(const float* __restrict__ Wfc, const float* __restrict__ bo,
             const float* __restrict__ bfc, float* __restrict__ bcomb) {
  __shared__ float red[256];
  int r = threadIdx.x >> 4, c = threadIdx.x & 15;
  int row = blockIdx.x * 16 + r;
  float s = 0.0f;
  for (int k = c; k < 256; k += 16) s = fmaf(Wfc[(size_t)row * 256 + k], bo[k], s);
  red[threadIdx.x] = s;
  __syncthreads();
  if (c == 0) {
    float t = 0.0f;
#pragma unroll
    for (int i = 0; i < 16; ++i) t += red[r * 16 + i];
    bcomb[row] = t + bfc[row];
  }
}

// ---------------------------------------------------------------------------
// expmap0 on Q,K rows -> bf16 rows + tables.
// Q rows -> qtab4 = (qq, ALPHA*log2 B, B, 0); K rows -> ktab2 = (kk, B),
// klgb = ALPHA*log2 B.  B = 1 - tanh^2 = 4 ex/(1+ex)^2 (cancellation-free).
__global__ __launch_bounds__(256)
void prep_qk(const float* __restrict__ Qf, const float* __restrict__ Kf,
             __bf16* __restrict__ Qbf, __bf16* __restrict__ Kbf,
             float4* __restrict__ qtab4, float2* __restrict__ ktab2,
             float* __restrict__ klgb) {
  int idx = blockIdx.x * 256 + threadIdx.x;   // 0..65535
  const bool isQ = idx < 32768;
  const int i2 = isQ ? idx : idx - 32768;
  const float* src = (isQ ? Qf : Kf) + (size_t)i2 * 32;
  __bf16* dst = (isQ ? Qbf : Kbf) + (size_t)i2 * 32;
  float v[32];
  float ss = 0.0f;
#pragma unroll
  for (int i = 0; i < 8; ++i) {
    float4 v4 = *(const float4*)&src[i * 4];
    v[i*4+0] = v4.x; v[i*4+1] = v4.y; v[i*4+2] = v4.z; v[i*4+3] = v4.w;
    ss = fmaf(v4.x, v4.x, ss); ss = fmaf(v4.y, v4.y, ss);
    ss = fmaf(v4.z, v4.z, ss); ss = fmaf(v4.w, v4.w, ss);
  }
  ss = fmaxf(ss, 1e-12f);
  float x  = sqrtf(ss);
  float ex = fast_exp2(-2.8853900817779268f * x);       // e^{-2x}
  float opex = 1.0f + ex;
  float th = (1.0f - ex) / opex;
  float sc = th / x;
  float qq = th * th;
  float Bv = 4.0f * ex / (opex * opex);                  // 1 - qq, exact
  float lgB = 2.0f - 2.8853900817779268f * x - 2.0f * fast_log2(opex);
  if (isQ) qtab4[i2] = float4{qq, ALPHA * lgB, Bv, 0.0f};
  else { ktab2[i2] = float2{qq, Bv}; klgb[i2] = ALPHA * lgB; }
  union { __bf16 h[8]; uint4 u; } pk;
#pragma unroll
  for (int blk = 0; blk < 4; ++blk) {
#pragma unroll
    for (int j = 0; j < 8; ++j) pk.h[j] = (__bf16)(v[blk * 8 + j] * sc);
    *(uint4*)(dst + blk * 8) = pk.u;
  }
}

// ---------------------------------------------------------------------------
// V[bh][t][dh] fp32 -> V^T[bh][dh][t] bf16.
__global__ __launch_bounds__(256)
void prep_vt(const float* __restrict__ Vf, __bf16* __restrict__ Vt) {
  int g = blockIdx.x * 256 + threadIdx.x;     // 0..131071
  int bh = g >> 13, rem = g & 8191;
  int tb = rem >> 5, dh = rem & 31;
  const float* src = Vf + (((size_t)bh * 2048 + tb * 8) * 32) + dh;
  union { __bf16 h[8]; uint4 u; } pk;
#pragma unroll
  for (int e = 0; e < 8; ++e) pk.h[e] = (__bf16)src[e * 32];
  *(uint4*)(Vt + ((size_t)bh * 32 + dh) * 2048 + tb * 8) = pk.u;
}

// ---------------------------------------------------------------------------
// Flash attention with MFMA + clip fast path. Grid (32, 4, 16), 4 waves/block.
__global__ __launch_bounds__(256)
void attn_mfma(const __bf16* __restrict__ Qbf, const __bf16* __restrict__ Kbf,
               const __bf16* __restrict__ Vt,  const float4* __restrict__ qtab4,
               const float2* __restrict__ ktab2, const float* __restrict__ klgb,
               float* __restrict__ PN, float* __restrict__ PD) {
  __shared__ __bf16 Pt[4][16][72];   // per-wave P^T buffer, pitch 72
  const int tid = threadIdx.x;
  const int wid = tid >> 6, lane = tid & 63;
  const int l15 = lane & 15, lg = lane >> 4;          // lg in 0..3
  const int tc = blockIdx.y;                          // t-chunk 0..3
  const int bh = blockIdx.z;
  const int s0 = blockIdx.x * 64 + wid * 16;

  bf16x8 qfrag = *(const bf16x8*)(Qbf + ((size_t)bh * 2048 + s0 + l15) * 32 + lg * 8);
  float4 qt = qtab4[bh * 2048 + s0 + l15];
  const float qq = qt.x, Bq = qt.z;
  const float eminRow = EMIN - qt.y;     // per-row clip floor (row scale cancels)
  // Clipped weight is lane-constant: precompute fp32 + bf16-packed forms.
  const float wclip = fast_exp2(eminRow);
  const __bf16 wclip_b = (__bf16)wclip;
  union { __bf16 h[4]; uint2 u2; } pclip;
  pclip.h[0] = wclip_b; pclip.h[1] = wclip_b; pclip.h[2] = wclip_b; pclip.h[3] = wclip_b;
  const float wclip4 = 4.0f * (float)wclip_b;  // den matches bf16-quantized P

  const __bf16* Kbase = Kbf + (size_t)bh * 2048 * 32;
  const __bf16* Vbase = Vt + (size_t)bh * 32 * 2048;
  const float2* kt2 = ktab2 + bh * 2048;
  const float*  kg  = klgb + bh * 2048;
  __bf16* Pw = &Pt[wid][0][0];

  f32x4 accO0 = {0.f, 0.f, 0.f, 0.f};
  f32x4 accO1 = {0.f, 0.f, 0.f, 0.f};
  float den = 0.0f;
  const f32x4 zero = {0.f, 0.f, 0.f, 0.f};

  const int tbeg = tc * 512;
  for (int t0 = tbeg; t0 < tbeg + 512; t0 += 64) {
#pragma unroll
    for (int sub = 0; sub < 4; ++sub) {
      const int tt = t0 + sub * 16;
      bf16x8 kfrag = *(const bf16x8*)(Kbase + (size_t)(tt + l15) * 32 + lg * 8);
      const int tk = tt + lg * 4;
      float4 kA = *(const float4*)&kt2[tk];       // kk0 B0 kk1 B1
      float4 kB = *(const float4*)&kt2[tk + 2];   // kk2 B2 kk3 B3
      f32x4 S = __builtin_amdgcn_mfma_f32_16x16x32_bf16(kfrag, qfrag, zero, 0, 0, 0);
      float kkv[4] = {kA.x, kA.z, kB.x, kB.z};
      float Bkv[4] = {kA.y, kA.w, kB.y, kB.w};
      float dv[4];
      bool ok = true;
#pragma unroll
      for (int r = 0; r < 4; ++r) {
        float qk2 = S[r] + S[r];
        float d = fmaf(qq, kkv[r], 1.0f) - qk2;    // Mobius denom (>0)
        dv[r] = d;
        // clip <=> 1-n^2 = BqBk/d <= chi  <=>  BqBk - chi*d <= 0
        ok &= (fmaf(-CHI, d, Bq * Bkv[r]) <= 0.0f);
      }
      if (__all((int)ok)) {
        den += wclip4;
        *(uint2*)&Pw[l15 * 72 + sub * 16 + lg * 4] = pclip.u2;
      } else {
        float w[4];
#pragma unroll
        for (int r = 0; r < 4; ++r) {
          float qk2 = S[r] + S[r];
          float u = (qq + kkv[r]) - qk2;           // ||q-k||^2
          float d = dv[r];
          float p = fmaxf(u * d, 0.0f);
          float sq = sqrtf(p);
          float m = fmaf(2.0f, sq, u + d);         // (sqrt d + sqrt u)^2
          float e = fmaf(-ALPHA, fast_log2(m), kg[tk + r]);
          e = fmaxf(e, eminRow);
          w[r] = fast_exp2(e);
        }
        den += (w[0] + w[1]) + (w[2] + w[3]);
        union { __bf16 h[4]; uint2 u2; } pk;
        pk.h[0] = (__bf16)w[0]; pk.h[1] = (__bf16)w[1];
        pk.h[2] = (__bf16)w[2]; pk.h[3] = (__bf16)w[3];
        *(uint2*)&Pw[l15 * 72 + sub * 16 + lg * 4] = pk.u2;
      }
    }
    // PV: O[s][dh] += P[s][t] * V[t][dh]  (wave-private LDS, no barrier)
#pragma unroll
    for (int th = 0; th < 2; ++th) {
      bf16x8 pfrag = *(const bf16x8*)&Pw[l15 * 72 + th * 32 + lg * 8];
      bf16x8 v0 = *(const bf16x8*)(Vbase + (size_t)(l15) * 2048 + t0 + th * 32 + lg * 8);
      bf16x8 v1 = *(const bf16x8*)(Vbase + (size_t)(16 + l15) * 2048 + t0 + th * 32 + lg * 8);
      accO0 = __builtin_amdgcn_mfma_f32_16x16x32_bf16(pfrag, v0, accO0, 0, 0, 0);
      accO1 = __builtin_amdgcn_mfma_f32_16x16x32_bf16(pfrag, v1, accO1, 0, 0, 0);
    }
  }
  den += __shfl_xor(den, 16);
  den += __shfl_xor(den, 32);
  size_t pbase = ((size_t)tc * 16 + bh) * 2048;
  if (lg == 0) PD[pbase + s0 + l15] = den;
#pragma unroll
  for (int r = 0; r < 4; ++r) {
    int sl = lg * 4 + r;
    size_t row = (pbase + s0 + sl) * 32;
    PN[row + l15]      = accO0[r];
    PN[row + 16 + l15] = accO1[r];
  }
}

// ---------------------------------------------------------------------------
// Sum the 4 t-chunk partials, normalize, write attention out in [B,S,D].
__global__ __launch_bounds__(256)
void combine4(const float* __restrict__ PN, const float* __restrict__ PD,
              float* __restrict__ AO) {
  int idx = blockIdx.x * 256 + threadIdx.x;   // 0..32767 = (bh, s)
  int bh = idx >> 11, s = idx & 2047;
  int b = bh >> 3, h = bh & 7;
  float den = 0.0f;
#pragma unroll
  for (int c = 0; c < 4; ++c) den += PD[((size_t)c * 16 + bh) * 2048 + s];
  float r = 1.0f / den;
  size_t ob = ((size_t)b * 2048 + s) * 256 + h * 32;
#pragma unroll
  for (int i = 0; i < 8; ++i) {
    float4 sum = {0.0f, 0.0f, 0.0f, 0.0f};
#pragma unroll
    for (int c = 0; c < 4; ++c) {
      float4 v = *(const float4*)&PN[((((size_t)c * 16 + bh) * 2048 + s) * 32) + i * 4];
      sum.x += v.x; sum.y += v.y; sum.z += v.z; sum.w += v.w;
    }
    sum.x *= r; sum.y *= r; sum.z *= r; sum.w *= r;
    *(float4*)&AO[ob + i * 4] = sum;
  }
}

// ---------------------------------------------------------------------------
extern "C" void kernel_launch(void* const* d_in, const int* in_sizes, int n_in,
                              void* d_out, int out_size, void* d_ws, size_t ws_size,
                              hipStream_t stream) {
  const float* x   = (const float*)d_in[0];
  const float* Wq  = (const float*)d_in[1];
  const float* bq  = (const float*)d_in[2];
  const float* Wk  = (const float*)d_in[3];
  const float* bk  = (const float*)d_in[4];
  const float* Wv  = (const float*)d_in[5];
  const float* bv  = (const float*)d_in[6];
  const float* Wo  = (const float*)d_in[7];
  const float* bo  = (const float*)d_in[8];
  const float* Wfc = (const float*)d_in[9];
  const float* bfc = (const float*)d_in[10];

  float* ws = (float*)d_ws;
  // Workspace layout (floats); total ~9.13M floats = 36.5 MB.
  float* Qb  = ws;                                   // 1M
  float* Kb  = ws + (1 << 20);                       // 1M
  float* Vb  = ws + (2 << 20);                       // 1M
  __bf16* Qbf = (__bf16*)(ws + (3 << 20));           // 1M bf16
  __bf16* Kbf = (__bf16*)(ws + (3 << 20) + (1 << 19));
  __bf16* Vtb = (__bf16*)(ws + (4 << 20));           // 1M bf16
  float4* qtab4 = (float4*)(ws + (4 << 20) + (1 << 19));        // 128K floats
  float2* ktab2 = (float2*)(ws + (4 << 20) + (1 << 19) + (128 << 10)); // 64K floats
  float*  klgb  = ws + (4 << 20) + (1 << 19) + (192 << 10);     // 32K floats
  float* Wcomb  = ws + (4 << 20) + (1 << 19) + (224 << 10);     // 64K floats
  float* bcomb  = Wcomb + 65536;                                // 256
  float* PN = ws + (5 << 20);                        // [4][16][2048][32] = 4M
  float* PD = ws + (9 << 20);                        // 128K
  float* AO = Qb;                                    // reuse (dead after prep_qk)

  dim3 blk(256);
  gemm_qkv<<<dim3(64, 12), blk, 0, stream>>>(x, Wq, bq, Wk, bk, Wv, bv, Qb, Kb, Vb);
  prep_qk<<<dim3(256), blk, 0, stream>>>(Qb, Kb, Qbf, Kbf, qtab4, ktab2, klgb);
  prep_vt<<<dim3(512), blk, 0, stream>>>(Vb, Vtb);
  gemm_nn_small<<<dim3(4, 4), blk, 0, stream>>>(Wfc, Wo, Wcomb);
  bcomb_k<<<dim3(16), blk, 0, stream>>>(Wfc, bo, bfc, bcomb);
  attn_mfma<<<dim3(32, 4, 16), blk, 0, stream>>>(Qbf, Kbf, Vtb, qtab4, ktab2, klgb, PN, PD);
  combine4<<<dim3(128), blk, 0, stream>>>(PN, PD, AO);
  gemm64<<<dim3(64, 4), blk, 0, stream>>>(AO, Wcomb, bcomb, (float*)d_out, 256);
}

// Round 8
// 117.461 us; speedup vs baseline: 4.0068x; 1.2495x over previous
//
#include <hip/hip_runtime.h>
#include <cstdint>
#include <cstddef>

// Poincare-ball (hyperbolic) attention block. B=2, S=2048, D=256, H=8, dh=32, c=1.
//
// Round 8 = round 7 + one-line fix: fast-path den contribution is 8*wclip per
// lane (4 lanes per q-row are summed by the lg-reduction -> 32*wclip total),
// not 32*wclip per lane (which overcounted den by 4x on clipped halves).
//
//  - per 32-t half-tile, if all pairs clip (test BqBk <= chi*d, exact), the
//    PV contribution is rank-1: acc += wclip(s) * Vsum32[t-tile][dh]. No P
//    write/read, no PV MFMA, no V traffic. Rare mixed halves take the full
//    round-6 path (exact chain + PV MFMA from global V).
//  - K tile + per-t table staged in LDS once per BLOCK (global_load_lds,
//    16B, chunk-XOR source swizzle), instead of 4 redundant per-wave streams.
//  - s-blocks stagger their t-tile order to spread L2 hot lines.

#define ALPHA 0.17677669529663687f   // 1/sqrt(32)
#define EMIN  -3.1129694f            // -ALPHA * log2((2-1e-5)/1e-5)  (clip)
#define CHI   1.95e-5f               // conservative 1-(1-1e-5)^2

typedef __bf16 bf16x8 __attribute__((ext_vector_type(8)));
typedef float  f32x4  __attribute__((ext_vector_type(4)));

__device__ __forceinline__ float fast_log2(float x) { return __builtin_amdgcn_logf(x); }
__device__ __forceinline__ float fast_exp2(float x) { return __builtin_amdgcn_exp2f(x); }

__device__ __forceinline__ void load_lds16(const void* g, void* l) {
  __builtin_amdgcn_global_load_lds((const __attribute__((address_space(1))) void*)g,
                                   (__attribute__((address_space(3))) void*)l, 16, 0, 0);
}

// ---------------------------------------------------------------------------
// Shared GEMM inner body: C_tile[64x64] += A[m0..][k] * W[n0..][k]^T.
__device__ __forceinline__ void gemm_tile_nt(const float* __restrict__ A,
                                             const float* __restrict__ W,
                                             int m0, int n0,
                                             float (*AsT)[68], float (*WsT)[68],
                                             float acc[4][4]) {
  const int tid = threadIdx.x;
  const int ty = tid >> 4, tx = tid & 15;
  for (int k0 = 0; k0 < 256; k0 += 32) {
#pragma unroll
    for (int jj = 0; jj < 2; ++jj) {
      int j = tid * 2 + jj;
      int r = j >> 3;
      int c4 = (j & 7) << 2;
      float4 av = *(const float4*)&A[(size_t)(m0 + r) * 256 + k0 + c4];
      float4 wv = *(const float4*)&W[(size_t)(n0 + r) * 256 + k0 + c4];
      AsT[c4 + 0][r] = av.x; AsT[c4 + 1][r] = av.y;
      AsT[c4 + 2][r] = av.z; AsT[c4 + 3][r] = av.w;
      WsT[c4 + 0][r] = wv.x; WsT[c4 + 1][r] = wv.y;
      WsT[c4 + 2][r] = wv.z; WsT[c4 + 3][r] = wv.w;
    }
    __syncthreads();
#pragma unroll
    for (int kk = 0; kk < 32; ++kk) {
      float4 a = *(const float4*)&AsT[kk][ty * 4];
      float4 b = *(const float4*)&WsT[kk][tx * 4];
      float av[4] = {a.x, a.y, a.z, a.w};
      float bv[4] = {b.x, b.y, b.z, b.w};
#pragma unroll
      for (int i = 0; i < 4; ++i)
#pragma unroll
        for (int j = 0; j < 4; ++j)
          acc[i][j] = fmaf(av[i], bv[j], acc[i][j]);
    }
    __syncthreads();
  }
}

// ---------------------------------------------------------------------------
// Fused QKV projection. Grid (64, 12).
__global__ __launch_bounds__(256)
void gemm_qkv(const float* __restrict__ x,
              const float* __restrict__ Wq, const float* __restrict__ bq,
              const float* __restrict__ Wk, const float* __restrict__ bk,
              const float* __restrict__ Wv, const float* __restrict__ bv,
              float* __restrict__ Qb, float* __restrict__ Kb, float* __restrict__ Vb) {
  __shared__ float AsT[32][68];
  __shared__ float WsT[32][68];
  const int wsel = blockIdx.y >> 2;
  const float* W    = wsel == 0 ? Wq : (wsel == 1 ? Wk : Wv);
  const float* bias = wsel == 0 ? bq : (wsel == 1 ? bk : bv);
  float* C          = wsel == 0 ? Qb : (wsel == 1 ? Kb : Vb);
  const int m0 = blockIdx.x * 64;
  const int n0 = (blockIdx.y & 3) * 64;
  float acc[4][4] = {};
  gemm_tile_nt(x, W, m0, n0, AsT, WsT, acc);
  const int ty = threadIdx.x >> 4, tx = threadIdx.x & 15;
#pragma unroll
  for (int i = 0; i < 4; ++i) {
    int m = m0 + ty * 4 + i;
    float4 o;
    o.x = acc[i][0] + bias[n0 + tx * 4 + 0];
    o.y = acc[i][1] + bias[n0 + tx * 4 + 1];
    o.z = acc[i][2] + bias[n0 + tx * 4 + 2];
    o.w = acc[i][3] + bias[n0 + tx * 4 + 3];
    int n = n0 + tx * 4;
    int h = n >> 5, d = n & 31;
    int b = m >> 11, s = m & 2047;
    *(float4*)&C[((size_t)((b << 3) + h) << 16) + (size_t)s * 32 + d] = o;
  }
}

// ---------------------------------------------------------------------------
// Plain NT GEMM: C = A @ W^T + bias. Grid (M/64, N/64).
__global__ __launch_bounds__(256)
void gemm64(const float* __restrict__ A, const float* __restrict__ W,
            const float* __restrict__ bias, float* __restrict__ C, int ldc) {
  __shared__ float AsT[32][68];
  __shared__ float WsT[32][68];
  const int m0 = blockIdx.x * 64;
  const int n0 = blockIdx.y * 64;
  float acc[4][4] = {};
  gemm_tile_nt(A, W, m0, n0, AsT, WsT, acc);
  const int ty = threadIdx.x >> 4, tx = threadIdx.x & 15;
#pragma unroll
  for (int i = 0; i < 4; ++i) {
    int m = m0 + ty * 4 + i;
    float4 o;
    o.x = acc[i][0] + bias[n0 + tx * 4 + 0];
    o.y = acc[i][1] + bias[n0 + tx * 4 + 1];
    o.z = acc[i][2] + bias[n0 + tx * 4 + 2];
    o.w = acc[i][3] + bias[n0 + tx * 4 + 3];
    *(float4*)&C[(size_t)m * ldc + n0 + tx * 4] = o;
  }
}

// ---------------------------------------------------------------------------
// Wcomb = Wfc @ Wo (NN, 256^3). Grid (4,4).
__global__ __launch_bounds__(256)
void gemm_nn_small(const float* __restrict__ Afc, const float* __restrict__ Bo,
                   float* __restrict__ C) {
  __shared__ float AsT[32][68];
  __shared__ float Bs[32][68];
  const int tid = threadIdx.x;
  const int ty = tid >> 4, tx = tid & 15;
  const int m0 = blockIdx.x * 64;
  const int n0 = blockIdx.y * 64;
  float acc[4][4] = {};
  for (int k0 = 0; k0 < 256; k0 += 32) {
#pragma unroll
    for (int jj = 0; jj < 2; ++jj) {
      int j = tid * 2 + jj;
      {
        int r = j >> 3, c4 = (j & 7) << 2;
        float4 av = *(const float4*)&Afc[(size_t)(m0 + r) * 256 + k0 + c4];
        AsT[c4 + 0][r] = av.x; AsT[c4 + 1][r] = av.y;
        AsT[c4 + 2][r] = av.z; AsT[c4 + 3][r] = av.w;
      }
      {
        int r = j >> 4, c4 = (j & 15) << 2;
        *(float4*)&Bs[r][c4] = *(const float4*)&Bo[(size_t)(k0 + r) * 256 + n0 + c4];
      }
    }
    __syncthreads();
#pragma unroll
    for (int kk = 0; kk < 32; ++kk) {
      float4 a = *(const float4*)&AsT[kk][ty * 4];
      float4 b = *(const float4*)&Bs[kk][tx * 4];
      float av[4] = {a.x, a.y, a.z, a.w};
      float bv[4] = {b.x, b.y, b.z, b.w};
#pragma unroll
      for (int i = 0; i < 4; ++i)
#pragma unroll
        for (int j2 = 0; j2 < 4; ++j2)
          acc[i][j2] = fmaf(av[i], bv[j2], acc[i][j2]);
    }
    __syncthreads();
  }
#pragma unroll
  for (int i = 0; i < 4; ++i) {
    float4 o = {acc[i][0], acc[i][1], acc[i][2], acc[i][3]};
    *(float4*)&C[(size_t)(m0 + ty * 4 + i) * 256 + n0 + tx * 4] = o;
  }
}

// ---------------------------------------------------------------------------
// bcomb = Wfc @ bo + bfc. Grid 16 blocks x 16 rows.
__global__ __launch_bounds__(256)
void bcomb_k(const float* __restrict__ Wfc, const float* __restrict__ bo,
             const float* __restrict__ bfc, float* __restrict__ bcomb) {
  __shared__ float red[256];
  int r = threadIdx.x >> 4, c = threadIdx.x & 15;
  int row = blockIdx.x * 16 + r;
  float s = 0.0f;
  for (int k = c; k < 256; k += 16) s = fmaf(Wfc[(size_t)row * 256 + k], bo[k], s);
  red[threadIdx.x] = s;
  __syncthreads();
  if (c == 0) {
    float t = 0.0f;
#pragma unroll
    for (int i = 0; i < 16; ++i) t += red[r * 16 + i];
    bcomb[row] = t + bfc[row];
  }
}

// ---------------------------------------------------------------------------
// expmap0 -> bf16 rows + tables.
// Q rows -> qtab4 = (qq, ALPHA*log2 B, B, 0).  K rows -> ktab4 = (kk, B, ALPHA*log2 B, 0).
__global__ __launch_bounds__(256)
void prep_qk(const float* __restrict__ Qf, const float* __restrict__ Kf,
             __bf16* __restrict__ Qbf, __bf16* __restrict__ Kbf,
             float4* __restrict__ qtab4, float4* __restrict__ ktab4) {
  int idx = blockIdx.x * 256 + threadIdx.x;   // 0..65535
  const bool isQ = idx < 32768;
  const int i2 = isQ ? idx : idx - 32768;
  const float* src = (isQ ? Qf : Kf) + (size_t)i2 * 32;
  __bf16* dst = (isQ ? Qbf : Kbf) + (size_t)i2 * 32;
  float v[32];
  float ss = 0.0f;
#pragma unroll
  for (int i = 0; i < 8; ++i) {
    float4 v4 = *(const float4*)&src[i * 4];
    v[i*4+0] = v4.x; v[i*4+1] = v4.y; v[i*4+2] = v4.z; v[i*4+3] = v4.w;
    ss = fmaf(v4.x, v4.x, ss); ss = fmaf(v4.y, v4.y, ss);
    ss = fmaf(v4.z, v4.z, ss); ss = fmaf(v4.w, v4.w, ss);
  }
  ss = fmaxf(ss, 1e-12f);
  float x  = sqrtf(ss);
  float ex = fast_exp2(-2.8853900817779268f * x);       // e^{-2x}
  float opex = 1.0f + ex;
  float th = (1.0f - ex) / opex;
  float sc = th / x;
  float qq = th * th;
  float Bv = 4.0f * ex / (opex * opex);                  // 1 - qq, exact
  float lgB = 2.0f - 2.8853900817779268f * x - 2.0f * fast_log2(opex);
  if (isQ) qtab4[i2] = float4{qq, ALPHA * lgB, Bv, 0.0f};
  else     ktab4[i2] = float4{qq, Bv, ALPHA * lgB, 0.0f};
  union { __bf16 h[8]; uint4 u; } pk;
#pragma unroll
  for (int blk = 0; blk < 4; ++blk) {
#pragma unroll
    for (int j = 0; j < 8; ++j) pk.h[j] = (__bf16)(v[blk * 8 + j] * sc);
    *(uint4*)(dst + blk * 8) = pk.u;
  }
}

// ---------------------------------------------------------------------------
// V[bh][t][dh] fp32 -> V^T[bh][dh][t] bf16.
__global__ __launch_bounds__(256)
void prep_vt(const float* __restrict__ Vf, __bf16* __restrict__ Vt) {
  int g = blockIdx.x * 256 + threadIdx.x;     // 0..131071
  int bh = g >> 13, rem = g & 8191;
  int tb = rem >> 5, dh = rem & 31;
  const float* src = Vf + (((size_t)bh * 2048 + tb * 8) * 32) + dh;
  union { __bf16 h[8]; uint4 u; } pk;
#pragma unroll
  for (int e = 0; e < 8; ++e) pk.h[e] = (__bf16)src[e * 32];
  *(uint4*)(Vt + ((size_t)bh * 32 + dh) * 2048 + tb * 8) = pk.u;
}

// ---------------------------------------------------------------------------
// Vsum32[bh][t32][dh] = sum over 32 t of V^T (bf16 values, f32 accumulate).
__global__ __launch_bounds__(256)
void vsum_k(const __bf16* __restrict__ Vt, float* __restrict__ Vsum) {
  int g = blockIdx.x * 256 + threadIdx.x;     // 0..32767
  int bh = g >> 11, rem = g & 2047;
  int t32 = rem >> 5, dh = rem & 31;
  const __bf16* src = Vt + ((size_t)bh * 32 + dh) * 2048 + t32 * 32;
  float s = 0.0f;
#pragma unroll
  for (int i = 0; i < 4; ++i) {
    bf16x8 v = *(const bf16x8*)&src[i * 8];
#pragma unroll
    for (int j = 0; j < 8; ++j) s += (float)v[j];
  }
  Vsum[((size_t)bh * 64 + t32) * 32 + dh] = s;
}

// ---------------------------------------------------------------------------
// Flash attention, clip-shortcut + LDS staging. Grid (32, 4, 16), 4 waves.
__global__ __launch_bounds__(256)
void attn_mfma(const __bf16* __restrict__ Qbf, const __bf16* __restrict__ Kbf,
               const __bf16* __restrict__ Vt,  const float4* __restrict__ qtab4,
               const float4* __restrict__ ktab4, const float* __restrict__ Vsum,
               float* __restrict__ PN, float* __restrict__ PD) {
  __shared__ __bf16 Kst[2048];       // 64 t x 32 dh, chunk-swizzled (4 KB)
  __shared__ float4 Tst[64];         // (kk, Bk, aLgBk, 0) per t (1 KB)
  __shared__ __bf16 Pt[4][16][72];   // rare-path per-wave P^T
  const int tid = threadIdx.x;
  const int wid = tid >> 6, lane = tid & 63;
  const int l15 = lane & 15, lg = lane >> 4;
  const int tc = blockIdx.y, bh = blockIdx.z;
  const int sblk = blockIdx.x;
  const int s0 = sblk * 64 + wid * 16;

  bf16x8 qfrag = *(const bf16x8*)(Qbf + ((size_t)bh * 2048 + s0 + l15) * 32 + lg * 8);
  float4 qt = qtab4[bh * 2048 + s0 + l15];
  const float qq = qt.x, Bq = qt.z;
  const float eminRow = EMIN - qt.y;
  const float wclipf = (float)(__bf16)fast_exp2(eminRow);   // bf16-quantized
  float wrow[4];
#pragma unroll
  for (int r = 0; r < 4; ++r)
    wrow[r] = (float)(__bf16)fast_exp2(EMIN - qtab4[bh * 2048 + s0 + lg * 4 + r].y);

  const __bf16* Kbase = Kbf + ((size_t)bh << 16);
  const __bf16* Vbase = Vt + ((size_t)bh << 16);
  const float4* Tbase = ktab4 + bh * 2048;
  const float*  VsBase = Vsum + (size_t)bh * 64 * 32;
  __bf16* Pw = &Pt[wid][0][0];

  f32x4 accO0 = {0.f, 0.f, 0.f, 0.f};
  f32x4 accO1 = {0.f, 0.f, 0.f, 0.f};
  float den = 0.0f;
  const f32x4 zero = {0.f, 0.f, 0.f, 0.f};
  const int tbeg = tc * 512;
  const int stag = sblk & 7;

  for (int i = 0; i < 8; ++i) {
    const int t0 = tbeg + (((i + stag) & 7) << 6);
    __syncthreads();                       // all waves done reading prev tile
    {   // stage K tile: wave w fills chunks [w*64, w*64+64) with source swizzle
      int slot = wid * 64 + lane;          // 16B chunk index 0..255
      int gch = slot ^ ((slot >> 2) & 3);  // involutive chunk XOR within row
      load_lds16(Kbase + (size_t)t0 * 32 + gch * 8, &Kst[wid * 512]);
      if (wid == 0) load_lds16(Tbase + t0 + lane, &Tst[0]);   // 64 x 16B
    }
    __syncthreads();                       // staged data visible (vmcnt drained)

#pragma unroll
    for (int h = 0; h < 2; ++h) {
      f32x4 S[2];
      bool ok = true;
#pragma unroll
      for (int s2 = 0; s2 < 2; ++s2) {
        const int sub = h * 2 + s2;
        const int R = sub * 16 + l15;
        const int slotR = R * 4 + (lg ^ (R & 3));
        bf16x8 kfrag = *(const bf16x8*)&Kst[slotR * 8];
        f32x4 Sv = __builtin_amdgcn_mfma_f32_16x16x32_bf16(kfrag, qfrag, zero, 0, 0, 0);
        S[s2] = Sv;
        const int tk = sub * 16 + lg * 4;
#pragma unroll
        for (int r = 0; r < 4; ++r) {
          float2 T2 = *(const float2*)&Tst[tk + r];     // (kk, Bk)
          float d = fmaf(qq, T2.x, 1.0f) - (Sv[r] + Sv[r]);
          ok &= (fmaf(-CHI, d, Bq * T2.y) <= 0.0f);
        }
      }
      if (__all((int)ok)) {
        // whole 32-t half clipped: rank-1 update, no PV.
        // den: 4 lanes (lg=0..3) share this q-row and are summed by the
        // lg-reduction below -> each adds 8*wclip so the total is 32*wclip.
        const int ti32 = (t0 >> 5) + h;
        float vsA = VsBase[ti32 * 32 + l15];
        float vsB = VsBase[ti32 * 32 + 16 + l15];
        den += 8.0f * wclipf;
#pragma unroll
        for (int r = 0; r < 4; ++r) {
          accO0[r] = fmaf(wrow[r], vsA, accO0[r]);
          accO1[r] = fmaf(wrow[r], vsB, accO1[r]);
        }
      } else {
        // rare: full exact chain for both subtiles, then PV MFMA (V from global)
#pragma unroll
        for (int s2 = 0; s2 < 2; ++s2) {
          const int sub = h * 2 + s2;
          const int tk = sub * 16 + lg * 4;
          f32x4 Sv = S[s2];
          float w[4];
#pragma unroll
          for (int r = 0; r < 4; ++r) {
            float4 T = Tst[tk + r];                  // kk, Bk, aLgBk
            float qk2 = Sv[r] + Sv[r];
            float u = (qq + T.x) - qk2;
            float d = fmaf(qq, T.x, 1.0f) - qk2;
            float p = fmaxf(u * d, 0.0f);
            float sq = sqrtf(p);
            float m = fmaf(2.0f, sq, u + d);
            float e = fmaf(-ALPHA, fast_log2(m), T.z);
            e = fmaxf(e, eminRow);
            w[r] = fast_exp2(e);
          }
          den += (w[0] + w[1]) + (w[2] + w[3]);
          union { __bf16 hh[4]; uint2 u2; } pk;
          pk.hh[0] = (__bf16)w[0]; pk.hh[1] = (__bf16)w[1];
          pk.hh[2] = (__bf16)w[2]; pk.hh[3] = (__bf16)w[3];
          *(uint2*)&Pw[l15 * 72 + sub * 16 + lg * 4] = pk.u2;
        }
        bf16x8 pfrag = *(const bf16x8*)&Pw[l15 * 72 + h * 32 + lg * 8];
        bf16x8 v0 = *(const bf16x8*)(Vbase + (size_t)l15 * 2048 + t0 + h * 32 + lg * 8);
        bf16x8 v1 = *(const bf16x8*)(Vbase + (size_t)(16 + l15) * 2048 + t0 + h * 32 + lg * 8);
        accO0 = __builtin_amdgcn_mfma_f32_16x16x32_bf16(pfrag, v0, accO0, 0, 0, 0);
        accO1 = __builtin_amdgcn_mfma_f32_16x16x32_bf16(pfrag, v1, accO1, 0, 0, 0);
      }
    }
  }
  den += __shfl_xor(den, 16);
  den += __shfl_xor(den, 32);
  size_t pbase = ((size_t)tc * 16 + bh) * 2048;
  if (lg == 0) PD[pbase + s0 + l15] = den;
#pragma unroll
  for (int r = 0; r < 4; ++r) {
    int sl = lg * 4 + r;
    size_t row = (pbase + s0 + sl) * 32;
    PN[row + l15]      = accO0[r];
    PN[row + 16 + l15] = accO1[r];
  }
}

// ---------------------------------------------------------------------------
// Sum the 4 t-chunk partials, normalize, write attention out in [B,S,D].
__global__ __launch_bounds__(256)
void combine4(const float* __restrict__ PN, const float* __restrict__ PD,
              float* __restrict__ AO) {
  int idx = blockIdx.x * 256 + threadIdx.x;   // 0..32767 = (bh, s)
  int bh = idx >> 11, s = idx & 2047;
  int b = bh >> 3, h = bh & 7;
  float den = 0.0f;
#pragma unroll
  for (int c = 0; c < 4; ++c) den += PD[((size_t)c * 16 + bh) * 2048 + s];
  float r = 1.0f / den;
  size_t ob = ((size_t)b * 2048 + s) * 256 + h * 32;
#pragma unroll
  for (int i = 0; i < 8; ++i) {
    float4 sum = {0.0f, 0.0f, 0.0f, 0.0f};
#pragma unroll
    for (int c = 0; c < 4; ++c) {
      float4 v = *(const float4*)&PN[((((size_t)c * 16 + bh) * 2048 + s) * 32) + i * 4];
      sum.x += v.x; sum.y += v.y; sum.z += v.z; sum.w += v.w;
    }
    sum.x *= r; sum.y *= r; sum.z *= r; sum.w *= r;
    *(float4*)&AO[ob + i * 4] = sum;
  }
}

// ---------------------------------------------------------------------------
extern "C" void kernel_launch(void* const* d_in, const int* in_sizes, int n_in,
                              void* d_out, int out_size, void* d_ws, size_t ws_size,
                              hipStream_t stream) {
  const float* x   = (const float*)d_in[0];
  const float* Wq  = (const float*)d_in[1];
  const float* bq  = (const float*)d_in[2];
  const float* Wk  = (const float*)d_in[3];
  const float* bk  = (const float*)d_in[4];
  const float* Wv  = (const float*)d_in[5];
  const float* bv  = (const float*)d_in[6];
  const float* Wo  = (const float*)d_in[7];
  const float* bo  = (const float*)d_in[8];
  const float* Wfc = (const float*)d_in[9];
  const float* bfc = (const float*)d_in[10];

  float* ws = (float*)d_ws;
  // Workspace (floats), ~9.13M total (~36.6 MB):
  float* Qb  = ws;                                   // 1M
  float* Kb  = ws + (1 << 20);                       // 1M
  float* Vb  = ws + (2 << 20);                       // 1M
  __bf16* Qbf = (__bf16*)(ws + (3 << 20));           // 1M bf16
  __bf16* Kbf = (__bf16*)(ws + (3 << 20) + (1 << 19));
  __bf16* Vtb = (__bf16*)(ws + (4 << 20));           // 1M bf16
  float4* qtab4 = (float4*)(ws + (4 << 20) + (1 << 19));            // 128K floats
  float4* ktab4 = (float4*)(ws + (4 << 20) + (1 << 19) + (1 << 17)); // 128K floats
  float*  Vsum  = ws + (4 << 20) + (1 << 19) + (2 << 17);           // 32K floats
  float* Wcomb  = Vsum + (1 << 15);                                 // 64K floats
  float* bcomb  = Wcomb + (1 << 16);                                // 256
  float* PN = ws + (5 << 20);                        // 4M
  float* PD = ws + (9 << 20);                        // 128K
  float* AO = Qb;                                    // reuse

  dim3 blk(256);
  gemm_qkv<<<dim3(64, 12), blk, 0, stream>>>(x, Wq, bq, Wk, bk, Wv, bv, Qb, Kb, Vb);
  prep_qk<<<dim3(256), blk, 0, stream>>>(Qb, Kb, Qbf, Kbf, qtab4, ktab4);
  prep_vt<<<dim3(512), blk, 0, stream>>>(Vb, Vtb);
  vsum_k<<<dim3(128), blk, 0, stream>>>(Vtb, Vsum);
  gemm_nn_small<<<dim3(4, 4), blk, 0, stream>>>(Wfc, Wo, Wcomb);
  bcomb_k<<<dim3(16), blk, 0, stream>>>(Wfc, bo, bfc, bcomb);
  attn_mfma<<<dim3(32, 4, 16), blk, 0, stream>>>(Qbf, Kbf, Vtb, qtab4, ktab4, Vsum, PN, PD);
  combine4<<<dim3(128), blk, 0, stream>>>(PN, PD, AO);
  gemm64<<<dim3(64, 4), blk, 0, stream>>>(AO, Wcomb, bcomb, (float*)d_out, 256);
}